// Round 2
// baseline (11978.992 us; speedup 1.0000x reference)
//
#include <hip/hip_runtime.h>
#include <math.h>
#include <stdint.h>

#define D     512
#define DFF   2048
#define BB    8
#define NH    8
#define HD    64
#define NV    32000
#define NL    4
#define TMAX  17
#define KC    64
#define STEPS 16
#define KTOP  50
#define PAD_ID 0
#define BOS_ID 2
#define EOS_ID 3

// ---------------- threefry2x32 (matches jax lowering exactly) ----------------
__device__ __forceinline__ void tf2x32(unsigned k0, unsigned k1, unsigned x0, unsigned x1,
                                       unsigned& o0, unsigned& o1)
{
  unsigned ks2 = k0 ^ k1 ^ 0x1BD11BDAu;
#define TFR(r) { x0 += x1; x1 = (x1 << (r)) | (x1 >> (32 - (r))); x1 ^= x0; }
  x0 += k0; x1 += k1;
  TFR(13) TFR(15) TFR(26) TFR(6)
  x0 += k1;  x1 += ks2 + 1u;
  TFR(17) TFR(29) TFR(16) TFR(24)
  x0 += ks2; x1 += k0 + 2u;
  TFR(13) TFR(15) TFR(26) TFR(6)
  x0 += k0;  x1 += k1 + 3u;
  TFR(17) TFR(29) TFR(16) TFR(24)
  x0 += k1;  x1 += ks2 + 4u;
  TFR(13) TFR(15) TFR(26) TFR(6)
  o0 = x0 + ks2; o1 = x1 + k0 + 5u;
#undef TFR
}

__device__ __forceinline__ float wredf(float v) {
  for (int o = 32; o; o >>= 1) v += __shfl_xor(v, o, 64);
  return v;
}
__device__ __forceinline__ float wredmaxf(float v) {
  for (int o = 32; o; o >>= 1) v = fmaxf(v, __shfl_xor(v, o, 64));
  return v;
}

// ---------------- device-scope barriers (state in ws, zeroed by init_k) ------
// group barrier: 32 blocks of one batch group
__device__ __forceinline__ void bar_sync(unsigned* cnt, unsigned* gen, unsigned nb, unsigned& lgen)
{
  __syncthreads();
  if (threadIdx.x == 0) {
    __threadfence();
    unsigned a = atomicAdd(cnt, 1u);
    if (a == nb - 1u) { atomicExch(cnt, 0u); __threadfence(); atomicAdd(gen, 1u); }
    unsigned target = ++lgen;
    while (__hip_atomic_load(gen, __ATOMIC_RELAXED, __HIP_MEMORY_SCOPE_AGENT) < target)
      __builtin_amdgcn_s_sleep(1);
    __threadfence();
  }
  __syncthreads();
}

// global barrier: 256 blocks, hierarchical (8 sub-counters then master)
__device__ __forceinline__ void gbar_sync(unsigned* bars, int b, unsigned& lgen)
{
  __syncthreads();
  if (threadIdx.x == 0) {
    __threadfence();
    unsigned a = atomicAdd(&bars[(8 + b) * 16], 1u);
    if (a == 31u) {
      atomicExch(&bars[(8 + b) * 16], 0u);
      unsigned m = atomicAdd(&bars[16 * 16], 1u);
      if (m == 7u) { atomicExch(&bars[16 * 16], 0u); __threadfence(); atomicAdd(&bars[16 * 16 + 1], 1u); }
    }
    unsigned target = ++lgen;
    while (__hip_atomic_load(&bars[16 * 16 + 1], __ATOMIC_RELAXED, __HIP_MEMORY_SCOPE_AGENT) < target)
      __builtin_amdgcn_s_sleep(1);
    __threadfence();
  }
  __syncthreads();
}

// ---------------- init: BOS token + finished flags + barrier state ----------
__global__ void init_k(int* toks, int* fin, unsigned* bars)
{
  int i = threadIdx.x;
  if (i < BB) { toks[i * TMAX + 0] = BOS_ID; fin[i] = 0; }
  if (i < 17 * 16) bars[i] = 0u;
}

// ---------------- cross-attention K/V precompute (one-time) -----------------
// grid.x = NL*KC*32 (gx = l*2048 + kpos*32 + jblk), grid.y = B, block 256
__global__ void cross_kv_k(const float* __restrict__ state, const float* __restrict__ qkvw,
                           const float* __restrict__ qkvb, float* __restrict__ cK,
                           float* __restrict__ cV)
{
  int gx = blockIdx.x, b = blockIdx.y, tid = threadIdx.x;
  int jblk = gx & 31, kpos = (gx >> 5) & 63, l = gx >> 11;
  int w = tid >> 6, lane = tid & 63;
  __shared__ __align__(16) float xsh[D];
  xsh[tid] = state[((size_t)b * KC + kpos) * D + tid];
  xsh[tid + 256] = state[((size_t)b * KC + kpos) * D + tid + 256];
  __syncthreads();
  for (int i = 0; i < 8; i++) {
    int j = jblk * 32 + w * 8 + i;          // 0..1023 (K rows then V rows)
    int row = D + j;
    const float4* wr = (const float4*)(qkvw + (((size_t)l * 2 + 1) * (3 * D) + row) * D);
    const float4* x4 = (const float4*)xsh;
    float acc = 0.f;
    for (int e = lane; e < 128; e += 64) {
      float4 a = wr[e], xx = x4[e];
      acc += a.x * xx.x + a.y * xx.y + a.z * xx.z + a.w * xx.w;
    }
    acc = wredf(acc);
    if (lane == 0) {
      float v = acc + qkvb[((size_t)l * 2 + 1) * (3 * D) + row];
      float* dst = (j < D) ? cK : cV;
      int jj = (j < D) ? j : j - D;
      dst[(((size_t)l * BB + b) * KC + kpos) * D + jj] = v;
    }
  }
}

// ---------------- the persistent decode megakernel --------------------------
extern "C" __global__ void __launch_bounds__(256)
decode_k(const float* __restrict__ emb, const float* __restrict__ qkv_w,
         const float* __restrict__ qkv_b, const float* __restrict__ out_w,
         const float* __restrict__ out_b, const float* __restrict__ f_w1,
         const float* __restrict__ f_b1, const float* __restrict__ f_w2,
         const float* __restrict__ f_b2, const float* __restrict__ lng,
         const float* __restrict__ lnb,
         const float* __restrict__ cK, const float* __restrict__ cV,
         float* __restrict__ sK, float* __restrict__ sV,
         float* __restrict__ xt, float* __restrict__ xcur,
         float* __restrict__ qbuf, float* __restrict__ aobuf,
         float* __restrict__ hbuf, float* __restrict__ lg,
         int* __restrict__ fin, unsigned* __restrict__ bars, int* __restrict__ toks)
{
  const int tid = threadIdx.x, bid = blockIdx.x;
  const int b = bid >> 5, g = bid & 31, w = tid >> 6, lane = tid & 63;
  unsigned lgen_grp = 0, lgen_glb = 0;
  unsigned* gcnt = &bars[b * 16];
  unsigned* ggen = &bars[b * 16 + 1];

  __shared__ __align__(16) float sA[4096];   // x / ao / hb / xs8 / bv
  __shared__ __align__(16) float sB[512];    // q
  __shared__ float sC[NH * TMAX];            // scores
  __shared__ float sRed[4];
  __shared__ unsigned sHist[256];
  __shared__ unsigned sPfx, sKr;
  __shared__ int sTok;

  const float SQD = (float)22.627416997969522;
  const float PEC = (float)(9.210340371976184 / 512.0);
  const float SQRT2 = (float)1.4142135623730951;

  // block_sum via macro-ish lambda
  auto block_sum = [&](float v) -> float {
    v = wredf(v);
    __syncthreads();
    if (lane == 0) sRed[w] = v;
    __syncthreads();
    return sRed[0] + sRed[1] + sRed[2] + sRed[3];
  };
  auto ln_lds = [&](const float* xtb, const float* gg, const float* bbv, float* xs) {
    float v0 = xtb[tid], v1 = xtb[tid + 256];
    float mu = block_sum(v0 + v1) * (1.0f / 512.0f);
    float d0 = v0 - mu, d1 = v1 - mu;
    float sd = sqrtf(block_sum(d0 * d0 + d1 * d1) * (1.0f / 512.0f) + 1e-5f);
    xs[tid] = d0 / sd * gg[tid] + bbv[tid];
    xs[tid + 256] = d1 / sd * gg[tid + 256] + bbv[tid + 256];
    __syncthreads();
  };

  // ---- stage E0: embed BOS at position 0 into xcur ----
  if (g == 0) {
    for (int j = tid; j < D; j += 256) {
      float e = emb[(size_t)BOS_ID * D + j] * SQD;
      float omega = expf(-(float)(j & ~1) * PEC);
      float val = 0.f * omega;
      float pe = (j & 1) ? cosf(val) : sinf(val);
      xcur[b * D + j] = e + pe;
    }
  }
  bar_sync(gcnt, ggen, 32, lgen_grp);

  for (int t = 0; t < STEPS; ++t) {
    const int T = t + 1;
    for (int l = 0; l < NL; ++l) {
      const float* wqkv0 = qkv_w + ((size_t)l * 2 + 0) * (3 * D) * D;
      const float* bqkv0 = qkv_b + ((size_t)l * 2 + 0) * (3 * D);
      const float* wqkv1 = qkv_w + ((size_t)l * 2 + 1) * (3 * D) * D;
      const float* bqkv1 = qkv_b + ((size_t)l * 2 + 1) * (3 * D);
      const float* wo0 = out_w + ((size_t)l * 2 + 0) * D * D;
      const float* bo0 = out_b + ((size_t)l * 2 + 0) * D;
      const float* wo1 = out_w + ((size_t)l * 2 + 1) * D * D;
      const float* bo1 = out_b + ((size_t)l * 2 + 1) * D;

      // ---- S1: (LN) + QKV projection ----
      if (l == 0) {
        sA[tid] = xcur[b * D + tid]; sA[tid + 256] = xcur[b * D + tid + 256];
        __syncthreads();
      } else {
        ln_lds(xt + b * D, lng + ((size_t)l * 3 - 1) * D, lnb + ((size_t)l * 3 - 1) * D, sA);
        if (g == 0) { xcur[b * D + tid] = sA[tid]; xcur[b * D + tid + 256] = sA[tid + 256]; }
      }
      for (int i = 0; i < 12; i++) {
        int j = g * 48 + w * 12 + i;                       // 0..1535
        const float4* wr = (const float4*)(wqkv0 + (size_t)j * D);
        const float4* x4 = (const float4*)sA;
        float acc = 0.f;
        for (int e = lane; e < 128; e += 64) {
          float4 a = wr[e], xx = x4[e];
          acc += a.x * xx.x + a.y * xx.y + a.z * xx.z + a.w * xx.w;
        }
        acc = wredf(acc);
        if (lane == 0) {
          float v = acc + bqkv0[j];
          if (j < D)          qbuf[b * D + j] = v;
          else if (j < 2 * D) sK[(((size_t)l * BB + b) * TMAX + t) * D + (j - D)] = v;
          else                sV[(((size_t)l * BB + b) * TMAX + t) * D + (j - 2 * D)] = v;
        }
      }
      bar_sync(gcnt, ggen, 32, lgen_grp);

      // ---- S2: self-attention (redundant per block) + Wo + residual ----
      sB[tid] = qbuf[b * D + tid]; sB[tid + 256] = qbuf[b * D + tid + 256];
      __syncthreads();
      for (int idx = tid; idx < NH * T; idx += 256) {
        int h = idx / T, k = idx - h * T;
        const float4* Kr = (const float4*)(sK + (((size_t)l * BB + b) * TMAX + k) * D + h * HD);
        const float4* qh = (const float4*)(sB + h * HD);
        float sc = 0.f;
        for (int e = 0; e < 16; e++) {
          float4 kv = Kr[e], qv = qh[e];
          sc += kv.x * qv.x + kv.y * qv.y + kv.z * qv.z + kv.w * qv.w;
        }
        sC[h * TMAX + k] = sc * 0.125f;
      }
      __syncthreads();
      if (tid < NH) {
        float m = -INFINITY;
        for (int k = 0; k < T; k++) m = fmaxf(m, sC[tid * TMAX + k]);
        float den = 0.f;
        for (int k = 0; k < T; k++) den += expf(sC[tid * TMAX + k] - m);
        for (int k = 0; k < T; k++) sC[tid * TMAX + k] = expf(sC[tid * TMAX + k] - m) / den;
      }
      __syncthreads();
      for (int df = tid; df < D; df += 256) {
        int h = df >> 6, d = df & 63;
        const float* Vb = sV + (((size_t)l * BB + b) * TMAX) * D + h * HD + d;
        float o = 0.f;
        for (int k = 0; k < T; k++) o += sC[h * TMAX + k] * Vb[(size_t)k * D];
        sA[512 + df] = o;
      }
      __syncthreads();
      for (int i = 0; i < 4; i++) {
        int j = g * 16 + w * 4 + i;                        // 0..511
        const float4* wr = (const float4*)(wo0 + (size_t)j * D);
        const float4* a4 = (const float4*)(sA + 512);
        float acc = 0.f;
        for (int e = lane; e < 128; e += 64) {
          float4 a = wr[e], xx = a4[e];
          acc += a.x * xx.x + a.y * xx.y + a.z * xx.z + a.w * xx.w;
        }
        acc = wredf(acc);
        if (lane == 0) xt[b * D + j] = acc + bo0[j] + sA[j];
      }
      bar_sync(gcnt, ggen, 32, lgen_grp);

      // ---- S3: LN0 + cross-Q projection + cross-attention (blocks g<8, h=g) ----
      if (g < NH) {
        int h = g;
        ln_lds(xt + b * D, lng + ((size_t)l * 3 + 0) * D, lnb + ((size_t)l * 3 + 0) * D, sA);
        if (g == 0) { xcur[b * D + tid] = sA[tid]; xcur[b * D + tid + 256] = sA[tid + 256]; }
        for (int i = 0; i < 16; i++) {
          int jj = w * 16 + i;                              // 0..63
          int j = h * HD + jj;                              // q row
          const float4* wr = (const float4*)(wqkv1 + (size_t)j * D);
          const float4* x4 = (const float4*)sA;
          float acc = 0.f;
          for (int e = lane; e < 128; e += 64) {
            float4 a = wr[e], xx = x4[e];
            acc += a.x * xx.x + a.y * xx.y + a.z * xx.z + a.w * xx.w;
          }
          acc = wredf(acc);
          if (lane == 0) sB[jj] = acc + bqkv1[j];
        }
        __syncthreads();
        if (tid < KC) {
          const float4* Kr = (const float4*)(cK + (((size_t)l * BB + b) * KC + tid) * D + h * HD);
          const float4* qh = (const float4*)sB;
          float sc = 0.f;
          for (int e = 0; e < 16; e++) {
            float4 kv = Kr[e], qv = qh[e];
            sc += kv.x * qv.x + kv.y * qv.y + kv.z * qv.z + kv.w * qv.w;
          }
          sC[tid] = sc * 0.125f;
        }
        __syncthreads();
        if (tid < KC) {
          float sc = sC[tid];
          float m = wredmaxf(sc);
          float e = expf(sc - m);
          float den = wredf(e);
          sC[tid] = e / den;
        }
        __syncthreads();
        if (tid < HD) {
          const float* Vb = cV + (((size_t)l * BB + b) * KC) * D + h * HD + tid;
          float o = 0.f;
          for (int k = 0; k < KC; k++) o += sC[k] * Vb[(size_t)k * D];
          aobuf[b * D + h * HD + tid] = o;
        }
      }
      bar_sync(gcnt, ggen, 32, lgen_grp);

      // ---- S4: Wo (cross) + residual ----
      sA[tid] = xcur[b * D + tid]; sA[tid + 256] = xcur[b * D + tid + 256];
      sA[512 + tid] = aobuf[b * D + tid]; sA[768 + tid] = aobuf[b * D + 256 + tid];
      __syncthreads();
      for (int i = 0; i < 4; i++) {
        int j = g * 16 + w * 4 + i;
        const float4* wr = (const float4*)(wo1 + (size_t)j * D);
        const float4* a4 = (const float4*)(sA + 512);
        float acc = 0.f;
        for (int e = lane; e < 128; e += 64) {
          float4 a = wr[e], xx = a4[e];
          acc += a.x * xx.x + a.y * xx.y + a.z * xx.z + a.w * xx.w;
        }
        acc = wredf(acc);
        if (lane == 0) xt[b * D + j] = acc + bo1[j] + sA[j];
      }
      bar_sync(gcnt, ggen, 32, lgen_grp);

      // ---- S5: LN1 + FFN1 + GELU ----
      ln_lds(xt + b * D, lng + ((size_t)l * 3 + 1) * D, lnb + ((size_t)l * 3 + 1) * D, sA);
      if (g == 0) { xcur[b * D + tid] = sA[tid]; xcur[b * D + tid + 256] = sA[tid + 256]; }
      for (int i = 0; i < 16; i++) {
        int j = g * 64 + w * 16 + i;                       // 0..2047
        const float4* wr = (const float4*)(f_w1 + (size_t)l * DFF * D + (size_t)j * D);
        const float4* x4 = (const float4*)sA;
        float acc = 0.f;
        for (int e = lane; e < 128; e += 64) {
          float4 a = wr[e], xx = x4[e];
          acc += a.x * xx.x + a.y * xx.y + a.z * xx.z + a.w * xx.w;
        }
        acc = wredf(acc);
        if (lane == 0) {
          float v = acc + f_b1[(size_t)l * DFF + j];
          v = v * (erff(v / SQRT2) + 1.0f) / 2.0f;
          hbuf[b * DFF + j] = v;
        }
      }
      bar_sync(gcnt, ggen, 32, lgen_grp);

      // ---- S6: FFN2 + residual ----
      for (int i = tid; i < DFF; i += 256) sA[512 + i] = hbuf[b * DFF + i];
      __syncthreads();
      for (int i = 0; i < 4; i++) {
        int j = g * 16 + w * 4 + i;
        const float4* wr = (const float4*)(f_w2 + (size_t)l * D * DFF + (size_t)j * DFF);
        const float4* h4 = (const float4*)(sA + 512);
        float acc = 0.f;
        for (int e = lane; e < 512; e += 64) {
          float4 a = wr[e], xx = h4[e];
          acc += a.x * xx.x + a.y * xx.y + a.z * xx.z + a.w * xx.w;
        }
        acc = wredf(acc);
        if (lane == 0) xt[b * D + j] = acc + f_b2[(size_t)l * D + j] + xcur[b * D + j];
      }
      if (l < NL - 1) bar_sync(gcnt, ggen, 32, lgen_grp);
      else            gbar_sync(bars, b, lgen_glb);
    } // l

    // ---- logits (global stage, emb read shared across batch) ----
    for (int bb2 = 0; bb2 < BB; bb2++)
      ln_lds(xt + (size_t)bb2 * D, lng + 11 * D, lnb + 11 * D, sA + bb2 * 512);
    {
      float4 xr0[BB], xr1[BB];
#pragma unroll
      for (int bb2 = 0; bb2 < BB; bb2++) {
        xr0[bb2] = ((const float4*)sA)[bb2 * 128 + lane];
        xr1[bb2] = ((const float4*)sA)[bb2 * 128 + 64 + lane];
      }
      for (int i = w; i < 125; i += 4) {
        int v = i * 256 + bid;
        const float4* er = (const float4*)(emb + (size_t)v * D);
        float4 e0 = er[lane], e1 = er[lane + 64];
        float acc[BB];
#pragma unroll
        for (int bb2 = 0; bb2 < BB; bb2++) {
          acc[bb2] = e0.x * xr0[bb2].x + e0.y * xr0[bb2].y + e0.z * xr0[bb2].z + e0.w * xr0[bb2].w
                   + e1.x * xr1[bb2].x + e1.y * xr1[bb2].y + e1.z * xr1[bb2].z + e1.w * xr1[bb2].w;
        }
#pragma unroll
        for (int bb2 = 0; bb2 < BB; bb2++) {
          float r = wredf(acc[bb2]);
          if (lane == 0) lg[(size_t)bb2 * NV + v] = r;
        }
      }
    }
    gbar_sync(bars, b, lgen_glb);

    // ---- top-k threshold + gumbel sample + next embed (block g==0 per group) ----
    if (g == 0) {
      if (tid == 0) { sPfx = 0u; sKr = KTOP; }
      for (int p = 0; p < 4; p++) {
        int shift = 24 - 8 * p;
        sHist[tid] = 0u;
        __syncthreads();
        unsigned prefix = sPfx;
        unsigned maskhi = (p == 0) ? 0u : (0xFFFFFFFFu << (shift + 8));
        for (int v = tid; v < NV; v += 256) {
          unsigned u = __float_as_uint(lg[(size_t)b * NV + v]);
          u = (u & 0x80000000u) ? ~u : (u | 0x80000000u);
          if (p == 0 || (u & maskhi) == prefix)
            atomicAdd(&sHist[(u >> shift) & 0xFFu], 1u);
        }
        __syncthreads();
        if (tid == 0) {
          unsigned k = sKr, cum = 0;
          for (int bin = 255; bin >= 0; bin--) {
            cum += sHist[bin];
            if (cum >= k) {
              sKr = k - (cum - sHist[bin]);
              sPfx = prefix | ((unsigned)bin << shift);
              break;
            }
          }
        }
        __syncthreads();
      }
      unsigned upf = sPfx;
      unsigned tb = (upf & 0x80000000u) ? (upf ^ 0x80000000u) : ~upf;
      float th = __uint_as_float(tb);

      unsigned k0, k1;
      tf2x32(0u, 1u, 0u, (unsigned)t, k0, k1);
      float best = -INFINITY; int bi = NV;
      for (int v = tid; v < NV; v += 256) {
        float lo = lg[(size_t)b * NV + v];
        if (lo >= th) {
          unsigned j = (unsigned)(b * NV + v);
          unsigned o0, o1;
          tf2x32(k0, k1, 0u, j, o0, o1);
          unsigned bits = o0 ^ o1;
          unsigned ub = (bits >> 9) | 0x3f800000u;
          float f = __uint_as_float(ub) - 1.0f;
          const float TINY = 1.17549435e-38f;
          float u = f * (1.0f - TINY) + TINY;
          u = fmaxf(TINY, u);
          float gmb = -logf(-logf(u));
          float s = lo + gmb;
          if (s > best || (s == best && v < bi)) { best = s; bi = v; }
        }
      }
      __syncthreads();           // sHist reuse
      sA[tid] = best; ((int*)sHist)[tid] = bi;
      __syncthreads();
      for (int o = 128; o; o >>= 1) {
        if (tid < o) {
          float ov = sA[tid + o]; int ox = ((int*)sHist)[tid + o];
          if (ov > sA[tid] || (ov == sA[tid] && ox < ((int*)sHist)[tid])) {
            sA[tid] = ov; ((int*)sHist)[tid] = ox;
          }
        }
        __syncthreads();
      }
      if (tid == 0) {
        int tok = ((int*)sHist)[0];
        if (fin[b]) tok = PAD_ID;
        toks[b * TMAX + t + 1] = tok;
        if (tok == EOS_ID) fin[b] = 1;
        sTok = tok;
      }
      __syncthreads();
      int tok = sTok;
      for (int j = tid; j < D; j += 256) {
        float e = emb[(size_t)tok * D + j] * SQD;
        float omega = expf(-(float)(j & ~1) * PEC);
        float val = (float)(t + 1) * omega;
        float pe = (j & 1) ? cosf(val) : sinf(val);
        xcur[b * D + j] = e + pe;
      }
    }
    gbar_sync(bars, b, lgen_glb);
  } // t
}

// ---------------- host orchestration ----------------
extern "C" void kernel_launch(void* const* d_in, const int* in_sizes, int n_in,
                              void* d_out, int out_size, void* d_ws, size_t ws_size,
                              hipStream_t stream)
{
  const float* state = (const float*)d_in[0];
  const float* emb   = (const float*)d_in[1];
  const float* qkv_w = (const float*)d_in[2];
  const float* qkv_b = (const float*)d_in[3];
  const float* out_w = (const float*)d_in[4];
  const float* out_b = (const float*)d_in[5];
  const float* f_w1  = (const float*)d_in[6];
  const float* f_b1  = (const float*)d_in[7];
  const float* f_w2  = (const float*)d_in[8];
  const float* f_b2  = (const float*)d_in[9];
  const float* lng   = (const float*)d_in[10];
  const float* lnb   = (const float*)d_in[11];

  float* ws = (float*)d_ws;
  float* cK   = ws;
  float* cV   = cK + (size_t)NL * BB * KC * D;       // 1048576
  float* sKb  = cV + (size_t)NL * BB * KC * D;       // 1048576
  float* sVb  = sKb + (size_t)NL * BB * TMAX * D;    // 278528
  float* xt   = sVb + (size_t)NL * BB * TMAX * D;    // 278528
  float* xcur = xt + BB * D;
  float* qbuf = xcur + BB * D;
  float* aobuf= qbuf + BB * D;
  float* hbuf = aobuf + BB * D;
  float* lg   = hbuf + BB * DFF;
  float* endf = lg + (size_t)BB * NV;
  int* fin       = (int*)endf;                        // 8 ints (pad to 16)
  unsigned* bars = (unsigned*)(endf + 16);            // 17*16 uints

  int* toks = (int*)d_out;

  init_k<<<1, 512, 0, stream>>>(toks, fin, bars);
  cross_kv_k<<<dim3(NL * KC * 32, BB), 256, 0, stream>>>(state, qkv_w, qkv_b, cK, cV);
  decode_k<<<256, 256, 0, stream>>>(emb, qkv_w, qkv_b, out_w, out_b,
                                    f_w1, f_b1, f_w2, f_b2, lng, lnb,
                                    cK, cV, sKb, sVb, xt, xcur, qbuf, aobuf, hbuf, lg,
                                    fin, bars, toks);
}

// Round 3
// 7679.090 us; speedup vs baseline: 1.5599x; 1.5599x over previous
//
#include <hip/hip_runtime.h>
#include <math.h>
#include <stdint.h>

#define D     512
#define DFF   2048
#define BB    8
#define NH    8
#define HD    64
#define NV    32000
#define NL    4
#define TMAX  17
#define KC    64
#define STEPS 16
#define KTOP  50
#define PAD_ID 0
#define BOS_ID 2
#define EOS_ID 3
#define SCOPE __HIP_MEMORY_SCOPE_AGENT

// ---------------- coherent (cache-bypassing) scalar access ------------------
__device__ __forceinline__ float ld1(const float* p) {
  return __hip_atomic_load(p, __ATOMIC_RELAXED, SCOPE);
}
__device__ __forceinline__ void st1(float* p, float v) {
  __hip_atomic_store(p, v, __ATOMIC_RELAXED, SCOPE);
}
__device__ __forceinline__ float2 ld2(const float* p) {
  union { double d; float2 f; } u;
  u.d = __hip_atomic_load((const double*)p, __ATOMIC_RELAXED, SCOPE);
  return u.f;
}
__device__ __forceinline__ void st2(float* p, float a, float b) {
  union { double d; float2 f; } u;
  u.f = make_float2(a, b);
  __hip_atomic_store((double*)p, u.d, __ATOMIC_RELAXED, SCOPE);
}

// ---------------- threefry2x32 (matches jax lowering exactly) ----------------
__device__ __forceinline__ void tf2x32(unsigned k0, unsigned k1, unsigned x0, unsigned x1,
                                       unsigned& o0, unsigned& o1)
{
  unsigned ks2 = k0 ^ k1 ^ 0x1BD11BDAu;
#define TFR(r) { x0 += x1; x1 = (x1 << (r)) | (x1 >> (32 - (r))); x1 ^= x0; }
  x0 += k0; x1 += k1;
  TFR(13) TFR(15) TFR(26) TFR(6)
  x0 += k1;  x1 += ks2 + 1u;
  TFR(17) TFR(29) TFR(16) TFR(24)
  x0 += ks2; x1 += k0 + 2u;
  TFR(13) TFR(15) TFR(26) TFR(6)
  x0 += k0;  x1 += k1 + 3u;
  TFR(17) TFR(29) TFR(16) TFR(24)
  x0 += k1;  x1 += ks2 + 4u;
  TFR(13) TFR(15) TFR(26) TFR(6)
  o0 = x0 + ks2; o1 = x1 + k0 + 5u;
#undef TFR
}

__device__ __forceinline__ float wredf(float v) {
  for (int o = 32; o; o >>= 1) v += __shfl_xor(v, o, 64);
  return v;
}
__device__ __forceinline__ float wredmaxf(float v) {
  for (int o = 32; o; o >>= 1) v = fmaxf(v, __shfl_xor(v, o, 64));
  return v;
}

#define DOT8(a0,a1,x0,x1) (a0.x*x0.x + a0.y*x0.y + a0.z*x0.z + a0.w*x0.w + \
                           a1.x*x1.x + a1.y*x1.y + a1.z*x1.z + a1.w*x1.w)

// ---------------- init: BOS tokens + barrier state --------------------------
__global__ void init_k(int* toks, unsigned* bars)
{
  int i = threadIdx.x;
  if (i < BB) toks[i * TMAX] = BOS_ID;
  for (int k = i; k < 640; k += 256) bars[k] = 0u;
}

// ---------------- cross-attention K/V precompute (one-time) -----------------
__global__ void cross_kv_k(const float* __restrict__ state, const float* __restrict__ qkvw,
                           const float* __restrict__ qkvb, float* __restrict__ cK,
                           float* __restrict__ cV)
{
  int gx = blockIdx.x, b = blockIdx.y, tid = threadIdx.x;
  int jblk = gx & 31, kpos = (gx >> 5) & 63, l = gx >> 11;
  int w = tid >> 6, lane = tid & 63;
  __shared__ __align__(16) float xsh[D];
  xsh[tid] = state[((size_t)b * KC + kpos) * D + tid];
  xsh[tid + 256] = state[((size_t)b * KC + kpos) * D + tid + 256];
  __syncthreads();
  for (int i = 0; i < 8; i++) {
    int j = jblk * 32 + w * 8 + i;          // 0..1023 (K rows then V rows)
    int row = D + j;
    const float4* wr = (const float4*)(qkvw + (((size_t)l * 2 + 1) * (3 * D) + row) * D);
    const float4* x4 = (const float4*)xsh;
    float acc = 0.f;
    for (int e = lane; e < 128; e += 64) {
      float4 a = wr[e], xx = x4[e];
      acc += a.x * xx.x + a.y * xx.y + a.z * xx.z + a.w * xx.w;
    }
    acc = wredf(acc);
    if (lane == 0) {
      float v = acc + qkvb[((size_t)l * 2 + 1) * (3 * D) + row];
      float* dst = (j < D) ? cK : cV;
      int jj = (j < D) ? j : j - D;
      dst[(((size_t)l * BB + b) * KC + kpos) * D + jj] = v;
    }
  }
}

// ---------------- persistent cooperative decode kernel ----------------------
extern "C" __global__ void __launch_bounds__(256, 1)
decode_k(const float* __restrict__ emb, const float* __restrict__ qkv_w,
         const float* __restrict__ qkv_b, const float* __restrict__ out_w,
         const float* __restrict__ out_b, const float* __restrict__ f_w1,
         const float* __restrict__ f_b1, const float* __restrict__ f_w2,
         const float* __restrict__ f_b2, const float* __restrict__ lng,
         const float* __restrict__ lnb,
         const float* __restrict__ cK, const float* __restrict__ cV,
         float* sKc, float* sVc, float* qbuf, float* ao, float* ao2,
         float* xt2, float* xt3, float* xt4, float* xn2, float* hbuf,
         float* xcur, float* lg, unsigned* bars, int* toks)
{
  const int tid = threadIdx.x, bid = blockIdx.x;
  const int w = tid >> 6, lane = tid & 63;
  unsigned lgen = 0;
  int finished = 0;    // only meaningful for tid==0 of blocks bid<8

  __shared__ __align__(16) float sX[4096];   // x-vectors (all 8 batch rows)
  __shared__ __align__(16) float sY[4096];   // ao/ao2 staging, xt2-row, hist
  __shared__ float sC[96];                   // attention scores
  __shared__ float sP[256];                  // per-wave V partials
  __shared__ float sQ[64];                   // cross-q head slice
  __shared__ float sRed[8], sMu[8], sSd[8];
  __shared__ unsigned sPfx, sKr;
  __shared__ int sTok;

  const float SQD = (float)22.627416997969522;
  const float PEC = (float)(9.210340371976184 / 512.0);
  const float SQRT2 = (float)1.4142135623730951;

  auto gbar = [&]() {
    asm volatile("s_waitcnt vmcnt(0)" ::: "memory");
    __syncthreads();
    if (tid == 0) {
      unsigned a = __hip_atomic_fetch_add(&bars[(bid & 15) * 32], 1u, __ATOMIC_RELAXED, SCOPE);
      if ((a & 15u) == 15u) {
        unsigned m = __hip_atomic_fetch_add(&bars[512], 1u, __ATOMIC_RELAXED, SCOPE);
        if ((m & 15u) == 15u)
          __hip_atomic_fetch_add(&bars[544], 1u, __ATOMIC_RELAXED, SCOPE);
      }
      ++lgen;
      while (__hip_atomic_load(&bars[544], __ATOMIC_RELAXED, SCOPE) < lgen)
        __builtin_amdgcn_s_sleep(1);
    }
    asm volatile("" ::: "memory");
    __syncthreads();
  };

  // load 8x512 from src (coherent) into sX, then LayerNorm each row (8 rows in parallel)
  auto loadLN8 = [&](const float* src, const float* gamma, const float* beta) {
    for (int ii = tid; ii < 2048; ii += 256) {
      float2 v = ld2(src + 2 * ii);
      sX[2 * ii] = v.x; sX[2 * ii + 1] = v.y;
    }
    __syncthreads();
    int b = w * 2 + (lane >> 5), l5 = lane & 31;
    float s = 0.f;
    for (int e = l5; e < D; e += 32) s += sX[b * D + e];
    for (int o = 16; o; o >>= 1) s += __shfl_xor(s, o, 64);
    if (l5 == 0) sMu[b] = s * (1.0f / 512.0f);
    __syncthreads();
    float mu = sMu[b], v2 = 0.f;
    for (int e = l5; e < D; e += 32) { float d0 = sX[b * D + e] - mu; v2 += d0 * d0; }
    for (int o = 16; o; o >>= 1) v2 += __shfl_xor(v2, o, 64);
    if (l5 == 0) sSd[b] = sqrtf(v2 * (1.0f / 512.0f) + 1e-5f);
    __syncthreads();
    for (int ii = tid; ii < 4096; ii += 256) {
      int b2 = ii >> 9, e = ii & 511;
      sX[ii] = (sX[ii] - sMu[b2]) / sSd[b2] * gamma[e] + beta[e];
    }
    __syncthreads();
  };

  // ---- initial: embed BOS at position 0 ----
  if (bid < BB) {
    int b = bid;
    for (int jj = tid; jj < 256; jj += 256) {
      int j0 = 2 * jj;
      float e0 = emb[(size_t)BOS_ID * D + j0] * SQD;
      float e1 = emb[(size_t)BOS_ID * D + j0 + 1] * SQD;
      st2(&xcur[b * D + j0], e0 + 0.0f, e1 + 1.0f);   // sin(0), cos(0)
    }
  }
  gbar();

  for (int t = 0; t < STEPS; ++t) {
    const int T = t + 1;
    for (int l = 0; l < NL; ++l) {
      const float* wqkv0 = qkv_w + ((size_t)l * 2 + 0) * (3 * D) * D;
      const float* bqkv0 = qkv_b + ((size_t)l * 2 + 0) * (3 * D);
      const float* wqkv1 = qkv_w + ((size_t)l * 2 + 1) * (3 * D) * D;
      const float* bqkv1 = qkv_b + ((size_t)l * 2 + 1) * (3 * D);
      const float* wo0 = out_w + ((size_t)l * 2 + 0) * D * D;
      const float* bo0 = out_b + ((size_t)l * 2 + 0) * D;
      const float* wo1 = out_w + ((size_t)l * 2 + 1) * D * D;
      const float* bo1 = out_b + ((size_t)l * 2 + 1) * D;

      // ---- P1: x1 into sX (raw xcur at l=0, else LN(xt4)); QKV projection ----
      if (l == 0) {
        for (int ii = tid; ii < 2048; ii += 256) {
          float2 v = ld2(xcur + 2 * ii);
          sX[2 * ii] = v.x; sX[2 * ii + 1] = v.y;
        }
        __syncthreads();
      } else {
        loadLN8(xt4, lng + ((size_t)(l - 1) * 3 + 2) * D, lnb + ((size_t)(l - 1) * 3 + 2) * D);
      }
      for (int i = w; i < 6; i += 4) {
        int j = bid * 6 + i;                          // 0..1535
        const float4* wr = (const float4*)(wqkv0 + (size_t)j * D);
        float4 a0 = wr[lane], a1 = wr[lane + 64];
        float bias = bqkv0[j];
        for (int b = 0; b < 8; b++) {
          const float4* x4 = (const float4*)(sX + b * D);
          float4 x0 = x4[lane], x1v = x4[lane + 64];
          float acc = DOT8(a0, a1, x0, x1v);
          acc = wredf(acc);
          if (lane == 0) {
            float v = acc + bias;
            if (j < D)          st1(&qbuf[b * D + j], v);
            else if (j < 2 * D) st1(&sKc[(((size_t)l * BB + b) * TMAX + t) * D + (j - D)], v);
            else                st1(&sVc[(((size_t)l * BB + b) * TMAX + t) * D + (j - 2 * D)], v);
          }
        }
      }
      gbar();

      // ---- P2: self-attention, 64 blocks = (b,h) ----
      if (bid < 64) {
        int b = bid >> 3, h = bid & 7;
        const float* Kb = sKc + ((size_t)l * BB + b) * TMAX * D + h * HD;
        const float* Vb = sVc + ((size_t)l * BB + b) * TMAX * D + h * HD;
        float qv = ld1(&qbuf[b * D + h * HD + lane]);
        for (int k = w; k < T; k += 4) {
          float sc = wredf(qv * ld1(&Kb[(size_t)k * D + lane]));
          if (lane == 0) sC[k] = sc * 0.125f;
        }
        __syncthreads();
        if (w == 0) {
          float v = (lane < T) ? sC[lane] : -INFINITY;
          float m = wredmaxf(v);
          float p = (lane < T) ? expf(v - m) : 0.f;
          float den = wredf(p);
          if (lane < T) sC[lane] = p / den;
        }
        __syncthreads();
        float acc = 0.f;
        for (int k = w; k < T; k += 4) acc += sC[k] * ld1(&Vb[(size_t)k * D + lane]);
        sP[w * 64 + lane] = acc;
        __syncthreads();
        if (w == 0)
          st1(&ao[b * D + h * HD + lane], sP[lane] + sP[64 + lane] + sP[128 + lane] + sP[192 + lane]);
      }
      gbar();

      // ---- P3: Wo(self)*ao + residual(sX=x1) -> xt2 ----
      for (int ii = tid; ii < 2048; ii += 256) {
        float2 v = ld2(ao + 2 * ii);
        sY[2 * ii] = v.x; sY[2 * ii + 1] = v.y;
      }
      __syncthreads();
      for (int idx = w; idx < 16; idx += 4) {
        int i = idx >> 3, b = idx & 7, j = bid * 2 + i;
        const float4* wr = (const float4*)(wo0 + (size_t)j * D);
        float4 a0 = wr[lane], a1 = wr[lane + 64];
        const float4* x4 = (const float4*)(sY + b * D);
        float4 x0 = x4[lane], x1v = x4[lane + 64];
        float acc = wredf(DOT8(a0, a1, x0, x1v));
        if (lane == 0) st1(&xt2[b * D + j], acc + bo0[j] + sX[b * D + j]);
      }
      gbar();

      // ---- P4: LN(xt2) -> x2; cross-Q; cross-attn.  64 blocks = (b,h) ----
      if (bid < 64) {
        int b = bid >> 3, h = bid & 7;
        {
          float2 v = ld2(xt2 + b * D + 2 * tid);
          sY[2 * tid] = v.x; sY[2 * tid + 1] = v.y;
        }
        __syncthreads();
        float v0 = sY[tid], v1 = sY[tid + 256];
        float s = wredf(v0 + v1);
        if (lane == 0) sRed[w] = s;
        __syncthreads();
        float mu = (sRed[0] + sRed[1] + sRed[2] + sRed[3]) * (1.0f / 512.0f);
        __syncthreads();
        float d0 = v0 - mu, d1 = v1 - mu;
        float vs = wredf(d0 * d0 + d1 * d1);
        if (lane == 0) sRed[w] = vs;
        __syncthreads();
        float sd = sqrtf((sRed[0] + sRed[1] + sRed[2] + sRed[3]) * (1.0f / 512.0f) + 1e-5f);
        const float* g0 = lng + ((size_t)l * 3 + 0) * D;
        const float* b0 = lnb + ((size_t)l * 3 + 0) * D;
        float x2a = d0 / sd * g0[tid] + b0[tid];
        float x2b = d1 / sd * g0[tid + 256] + b0[tid + 256];
        __syncthreads();
        sY[tid] = x2a; sY[tid + 256] = x2b;
        __syncthreads();
        if (h == 0) st2(&xn2[b * D + 2 * tid], sY[2 * tid], sY[2 * tid + 1]);
        for (int jj = w; jj < 64; jj += 4) {
          int j = h * HD + jj;
          const float4* wr = (const float4*)(wqkv1 + (size_t)j * D);
          float4 a0 = wr[lane], a1 = wr[lane + 64];
          const float4* x4 = (const float4*)sY;
          float4 x0 = x4[lane], x1v = x4[lane + 64];
          float acc = wredf(DOT8(a0, a1, x0, x1v));
          if (lane == 0) sQ[jj] = acc + bqkv1[j];
        }
        __syncthreads();
        float qv = sQ[lane];
        const float* Kb = cK + ((size_t)l * BB + b) * KC * D + h * HD;
        const float* Vb = cV + ((size_t)l * BB + b) * KC * D + h * HD;
        for (int k = w; k < KC; k += 4) {
          float sc = wredf(qv * Kb[(size_t)k * D + lane]);
          if (lane == 0) sC[k] = sc * 0.125f;
        }
        __syncthreads();
        if (w == 0) {
          float v = sC[lane];
          float m = wredmaxf(v);
          float p = expf(v - m);
          float den = wredf(p);
          sC[lane] = p / den;
        }
        __syncthreads();
        float acc = 0.f;
        for (int k = w; k < KC; k += 4) acc += sC[k] * Vb[(size_t)k * D + lane];
        sP[w * 64 + lane] = acc;
        __syncthreads();
        if (w == 0)
          st1(&ao2[b * D + h * HD + lane], sP[lane] + sP[64 + lane] + sP[128 + lane] + sP[192 + lane]);
      }
      gbar();

      // ---- P5: Wo(cross)*ao2 + residual(xn2=x2) -> xt3 ----
      for (int ii = tid; ii < 2048; ii += 256) {
        float2 v = ld2(ao2 + 2 * ii);
        sY[2 * ii] = v.x; sY[2 * ii + 1] = v.y;
      }
      __syncthreads();
      for (int idx = w; idx < 16; idx += 4) {
        int i = idx >> 3, b = idx & 7, j = bid * 2 + i;
        const float4* wr = (const float4*)(wo1 + (size_t)j * D);
        float4 a0 = wr[lane], a1 = wr[lane + 64];
        const float4* x4 = (const float4*)(sY + b * D);
        float4 x0 = x4[lane], x1v = x4[lane + 64];
        float acc = wredf(DOT8(a0, a1, x0, x1v));
        if (lane == 0) st1(&xt3[b * D + j], acc + bo1[j] + ld1(&xn2[b * D + j]));
      }
      gbar();

      // ---- P6: x3 = LN(xt3) in sX (persists); FFN1 + GELU -> hbuf ----
      loadLN8(xt3, lng + ((size_t)l * 3 + 1) * D, lnb + ((size_t)l * 3 + 1) * D);
      for (int i = w; i < 8; i += 4) {
        int j = bid * 8 + i;                          // 0..2047
        const float4* wr = (const float4*)(f_w1 + (size_t)l * DFF * D + (size_t)j * D);
        float4 a0 = wr[lane], a1 = wr[lane + 64];
        float bias = f_b1[(size_t)l * DFF + j];
        for (int b = 0; b < 8; b++) {
          const float4* x4 = (const float4*)(sX + b * D);
          float4 x0 = x4[lane], x1v = x4[lane + 64];
          float acc = wredf(DOT8(a0, a1, x0, x1v));
          if (lane == 0) {
            float v = acc + bias;
            v = v * (erff(v / SQRT2) + 1.0f) / 2.0f;
            st1(&hbuf[b * DFF + j], v);
          }
        }
      }
      gbar();

      // ---- P7: FFN2 + residual(sX=x3) -> xt4 ----
      for (int bx = 0; bx < 2; bx++) {
        int b = w + bx * 4;
        float hreg[32];
        const float* hb = hbuf + b * DFF + lane * 32;
#pragma unroll
        for (int kk = 0; kk < 16; kk++) {
          float2 v = ld2(hb + 2 * kk);
          hreg[2 * kk] = v.x; hreg[2 * kk + 1] = v.y;
        }
        for (int i = 0; i < 2; i++) {
          int j = bid * 2 + i;
          const float4* wr = (const float4*)(f_w2 + (size_t)l * D * DFF + (size_t)j * DFF + lane * 32);
          float acc = 0.f;
#pragma unroll
          for (int k4 = 0; k4 < 8; k4++) {
            float4 a = wr[k4];
            acc += a.x * hreg[k4 * 4] + a.y * hreg[k4 * 4 + 1]
                 + a.z * hreg[k4 * 4 + 2] + a.w * hreg[k4 * 4 + 3];
          }
          acc = wredf(acc);
          if (lane == 0)
            st1(&xt4[b * D + j], acc + f_b2[(size_t)l * D + j] + sX[b * D + j]);
        }
      }
      gbar();
    } // l

    // ---- logits: xf = LN(xt4) ; lg[b][v] = xf[b] . emb[v] ----
    loadLN8(xt4, lng + 11 * D, lnb + 11 * D);
    for (int i = w; i < 125; i += 4) {
      int v = i * 256 + bid;
      const float4* er = (const float4*)(emb + (size_t)v * D);
      float4 e0 = er[lane], e1 = er[lane + 64];
      float acc[8];
#pragma unroll
      for (int b = 0; b < 8; b++) {
        const float4* x4 = (const float4*)(sX + b * D);
        float4 x0 = x4[lane], x1v = x4[lane + 64];
        acc[b] = DOT8(e0, e1, x0, x1v);
      }
#pragma unroll
      for (int o = 32; o; o >>= 1) {
#pragma unroll
        for (int b = 0; b < 8; b++) acc[b] += __shfl_xor(acc[b], o, 64);
      }
      if (lane == 0) {
#pragma unroll
        for (int b = 0; b < 8; b++) st1(&lg[(size_t)b * NV + v], acc[b]);
      }
    }
    gbar();

    // ---- top-k threshold + gumbel-argmax + next-token embed (blocks 0..7) ----
    if (bid < BB) {
      int b = bid;
      unsigned* hist = (unsigned*)sY;
      if (tid == 0) { sPfx = 0u; sKr = KTOP; }
      for (int p = 0; p < 4; p++) {
        int shift = 24 - 8 * p;
        hist[tid] = 0u;
        __syncthreads();
        unsigned prefix = sPfx;
        unsigned maskhi = (p == 0) ? 0u : (0xFFFFFFFFu << (shift + 8));
        for (int v2 = tid; v2 < 16000; v2 += 256) {
          float2 f = ld2(&lg[(size_t)b * NV + 2 * v2]);
          unsigned u0 = __float_as_uint(f.x); u0 = (u0 & 0x80000000u) ? ~u0 : (u0 | 0x80000000u);
          unsigned u1 = __float_as_uint(f.y); u1 = (u1 & 0x80000000u) ? ~u1 : (u1 | 0x80000000u);
          if (p == 0 || (u0 & maskhi) == prefix) atomicAdd(&hist[(u0 >> shift) & 255u], 1u);
          if (p == 0 || (u1 & maskhi) == prefix) atomicAdd(&hist[(u1 >> shift) & 255u], 1u);
        }
        __syncthreads();
        if (tid == 0) {
          unsigned k = sKr, cum = 0;
          for (int bin = 255; bin >= 0; bin--) {
            cum += hist[bin];
            if (cum >= k) {
              sKr = k - (cum - hist[bin]);
              sPfx = prefix | ((unsigned)bin << shift);
              break;
            }
          }
        }
        __syncthreads();
      }
      unsigned upf = sPfx;
      unsigned tb = (upf & 0x80000000u) ? (upf ^ 0x80000000u) : ~upf;
      float th = __uint_as_float(tb);

      unsigned k0, k1;
      tf2x32(0u, 1u, 0u, (unsigned)t, k0, k1);
      float best = -INFINITY; int bi = NV;
      for (int v2 = tid; v2 < 16000; v2 += 256) {
        float2 f = ld2(&lg[(size_t)b * NV + 2 * v2]);
#pragma unroll
        for (int jj = 0; jj < 2; jj++) {
          float lo = jj ? f.y : f.x;
          int v = 2 * v2 + jj;
          if (lo >= th) {
            unsigned o0, o1;
            tf2x32(k0, k1, 0u, (unsigned)(b * NV + v), o0, o1);
            unsigned bits = o0 ^ o1;
            unsigned ub = (bits >> 9) | 0x3f800000u;
            float fu = __uint_as_float(ub) - 1.0f;
            const float TINY = 1.17549435e-38f;
            float u = fu * (1.0f - TINY) + TINY;
            u = fmaxf(TINY, u);
            float g = -logf(-logf(u));
            float s = lo + g;
            if (s > best || (s == best && v < bi)) { best = s; bi = v; }
          }
        }
      }
      __syncthreads();
      float* bv = sX; int* bx = (int*)(sX + 256);
      bv[tid] = best; bx[tid] = bi;
      __syncthreads();
      for (int o = 128; o; o >>= 1) {
        if (tid < o) {
          float ov = bv[tid + o]; int ox = bx[tid + o];
          if (ov > bv[tid] || (ov == bv[tid] && ox < bx[tid])) { bv[tid] = ov; bx[tid] = ox; }
        }
        __syncthreads();
      }
      if (tid == 0) {
        int tok = bx[0];
        if (finished) tok = PAD_ID;
        toks[b * TMAX + t + 1] = tok;
        if (tok == EOS_ID) finished = 1;
        sTok = tok;
      }
      __syncthreads();
      int tok = sTok;
      {
        int j0 = 2 * tid;
        float e0 = emb[(size_t)tok * D + j0] * SQD;
        float e1 = emb[(size_t)tok * D + j0 + 1] * SQD;
        float omega = expf(-(float)j0 * PEC);
        float val = (float)(t + 1) * omega;
        st2(&xcur[b * D + j0], e0 + sinf(val), e1 + cosf(val));
      }
    }
    gbar();
  } // t
}

// ---------------- host orchestration ----------------
extern "C" void kernel_launch(void* const* d_in, const int* in_sizes, int n_in,
                              void* d_out, int out_size, void* d_ws, size_t ws_size,
                              hipStream_t stream)
{
  const float* state = (const float*)d_in[0];
  const float* emb   = (const float*)d_in[1];
  const float* qkv_w = (const float*)d_in[2];
  const float* qkv_b = (const float*)d_in[3];
  const float* out_w = (const float*)d_in[4];
  const float* out_b = (const float*)d_in[5];
  const float* f_w1  = (const float*)d_in[6];
  const float* f_b1  = (const float*)d_in[7];
  const float* f_w2  = (const float*)d_in[8];
  const float* f_b2  = (const float*)d_in[9];
  const float* lng   = (const float*)d_in[10];
  const float* lnb   = (const float*)d_in[11];

  float* ws = (float*)d_ws;
  float* cK   = ws;                                    // 4*8*64*512
  float* cV   = cK + (size_t)NL * BB * KC * D;
  float* sKc  = cV + (size_t)NL * BB * KC * D;         // 4*8*17*512
  float* sVc  = sKc + (size_t)NL * BB * TMAX * D;
  float* qbuf = sVc + (size_t)NL * BB * TMAX * D;      // 4096 each below
  float* ao   = qbuf + BB * D;
  float* ao2  = ao + BB * D;
  float* xt2  = ao2 + BB * D;
  float* xt3  = xt2 + BB * D;
  float* xt4  = xt3 + BB * D;
  float* xn2  = xt4 + BB * D;
  float* hbuf = xn2 + BB * D;                          // 8*2048
  float* xcur = hbuf + BB * DFF;
  float* lg   = xcur + BB * D;                         // 8*32000
  unsigned* bars = (unsigned*)(lg + (size_t)BB * NV);  // 640 uints

  int* toks = (int*)d_out;

  init_k<<<1, 256, 0, stream>>>(toks, bars);
  cross_kv_k<<<dim3(NL * KC * 32, BB), 256, 0, stream>>>(state, qkv_w, qkv_b, cK, cV);
  decode_k<<<256, 256, 0, stream>>>(emb, qkv_w, qkv_b, out_w, out_b,
                                    f_w1, f_b1, f_w2, f_b2, lng, lnb,
                                    cK, cV, sKc, sVc, qbuf, ao, ao2,
                                    xt2, xt3, xt4, xn2, hbuf, xcur, lg, bars, toks);
}

// Round 5
// 7353.642 us; speedup vs baseline: 1.6290x; 1.0443x over previous
//
#include <hip/hip_runtime.h>
#include <math.h>
#include <stdint.h>

#define D     512
#define DFF   2048
#define BB    8
#define NH    8
#define HD    64
#define NV    32000
#define NL    4
#define TMAX  17
#define KC    64
#define STEPS 16
#define KTOP  50
#define PAD_ID 0
#define BOS_ID 2
#define EOS_ID 3
#define SCOPE __HIP_MEMORY_SCOPE_AGENT

// ---------------- coherent (cache-bypassing) access -------------------------
__device__ __forceinline__ float ld1(const float* p) {
  return __hip_atomic_load(p, __ATOMIC_RELAXED, SCOPE);
}
__device__ __forceinline__ void st1(float* p, float v) {
  __hip_atomic_store(p, v, __ATOMIC_RELAXED, SCOPE);
}
__device__ __forceinline__ float2 ld2(const float* p) {
  union { double d; float2 f; } u;
  u.d = __hip_atomic_load((const double*)p, __ATOMIC_RELAXED, SCOPE);
  return u.f;
}
__device__ __forceinline__ void st2(float* p, float a, float b) {
  union { double d; float2 f; } u;
  u.f = make_float2(a, b);
  __hip_atomic_store((double*)p, u.d, __ATOMIC_RELAXED, SCOPE);
}
__device__ __forceinline__ unsigned ldu(const unsigned* p) {
  return __hip_atomic_load(p, __ATOMIC_RELAXED, SCOPE);
}

// ---------------- threefry2x32 (matches jax lowering exactly) ----------------
__device__ __forceinline__ void tf2x32(unsigned k0, unsigned k1, unsigned x0, unsigned x1,
                                       unsigned& o0, unsigned& o1)
{
  unsigned ks2 = k0 ^ k1 ^ 0x1BD11BDAu;
#define TFR(r) { x0 += x1; x1 = (x1 << (r)) | (x1 >> (32 - (r))); x1 ^= x0; }
  x0 += k0; x1 += k1;
  TFR(13) TFR(15) TFR(26) TFR(6)
  x0 += k1;  x1 += ks2 + 1u;
  TFR(17) TFR(29) TFR(16) TFR(24)
  x0 += ks2; x1 += k0 + 2u;
  TFR(13) TFR(15) TFR(26) TFR(6)
  x0 += k0;  x1 += k1 + 3u;
  TFR(17) TFR(29) TFR(16) TFR(24)
  x0 += k1;  x1 += ks2 + 4u;
  TFR(13) TFR(15) TFR(26) TFR(6)
  o0 = x0 + ks2; o1 = x1 + k0 + 5u;
#undef TFR
}

__device__ __forceinline__ float wredf(float v) {
  for (int o = 32; o; o >>= 1) v += __shfl_xor(v, o, 64);
  return v;
}
__device__ __forceinline__ float wredmaxf(float v) {
  for (int o = 32; o; o >>= 1) v = fmaxf(v, __shfl_xor(v, o, 64));
  return v;
}
__device__ __forceinline__ unsigned monok(float f) {
  unsigned u = __float_as_uint(f);
  return (u & 0x80000000u) ? ~u : (u | 0x80000000u);
}

#define DOT8(a0,a1,x0,x1) (a0.x*x0.x + a0.y*x0.y + a0.z*x0.z + a0.w*x0.w + \
                           a1.x*x1.x + a1.y*x1.y + a1.z*x1.z + a1.w*x1.w)

// ---------------- init: BOS tokens + barrier state --------------------------
__global__ void init_k(int* toks, unsigned* bars)
{
  int i = threadIdx.x;
  if (i < BB) toks[i * TMAX] = BOS_ID;
  for (int k = i; k < 2048; k += 256) bars[k] = 0u;
}

// ---------------- cross-attention K/V precompute (one-time) -----------------
__global__ void cross_kv_k(const float* __restrict__ state, const float* __restrict__ qkvw,
                           const float* __restrict__ qkvb, float* __restrict__ cK,
                           float* __restrict__ cV)
{
  int gx = blockIdx.x, b = blockIdx.y, tid = threadIdx.x;
  int jblk = gx & 31, kpos = (gx >> 5) & 63, l = gx >> 11;
  int w = tid >> 6, lane = tid & 63;
  __shared__ __align__(16) float xsh[D];
  xsh[tid] = state[((size_t)b * KC + kpos) * D + tid];
  xsh[tid + 256] = state[((size_t)b * KC + kpos) * D + tid + 256];
  __syncthreads();
  for (int i = 0; i < 8; i++) {
    int j = jblk * 32 + w * 8 + i;          // 0..1023 (K rows then V rows)
    int row = D + j;
    const float4* wr = (const float4*)(qkvw + (((size_t)l * 2 + 1) * (3 * D) + row) * D);
    const float4* x4 = (const float4*)xsh;
    float acc = 0.f;
    for (int e = lane; e < 128; e += 64) {
      float4 a = wr[e], xx = x4[e];
      acc += a.x * xx.x + a.y * xx.y + a.z * xx.z + a.w * xx.w;
    }
    acc = wredf(acc);
    if (lane == 0) {
      float v = acc + qkvb[((size_t)l * 2 + 1) * (3 * D) + row];
      float* dst = (j < D) ? cK : cV;
      int jj = (j < D) ? j : j - D;
      dst[(((size_t)l * BB + b) * KC + kpos) * D + jj] = v;
    }
  }
}

// ---------------- persistent grouped decode kernel --------------------------
extern "C" __global__ void __launch_bounds__(256, 1)
decode_k(const float* __restrict__ emb, const float* __restrict__ qkv_w,
         const float* __restrict__ qkv_b, const float* __restrict__ out_w,
         const float* __restrict__ out_b, const float* __restrict__ f_w1,
         const float* __restrict__ f_b1, const float* __restrict__ f_w2,
         const float* __restrict__ f_b2, const float* __restrict__ lng,
         const float* __restrict__ lnb,
         const float* __restrict__ cK, const float* __restrict__ cV,
         float* Kc, float* Vc, float* qS, float* q2S,
         float* xt2, float* xt3, float* xt4, float* hB,
         float* xcur, float* lg, unsigned* bars, int* toks)
{
  const int tid = threadIdx.x, bid = blockIdx.x;
  const int g = bid & 7, gid = bid >> 3;     // group (=batch row, ~XCD) / in-group id
  const int w = tid >> 6, lane = tid & 63;
  unsigned gp = 0, glp = 0;
  int finished = 0;                          // used by gid==0 blocks only

  __shared__ __align__(16) unsigned char smem[65280];
  float* F = (float*)smem;
  float* sX1 = F;             // 512   (x1 / x3)
  float* sX2 = F + 512;       // 512   (x2)
  float* sQ  = F + 1024;      // 512
  float* sS  = F + 1536;      // 544   scores
  float* sSP = F + 2080;      // 544   softmax probs
  float* sAO = F + 2624;      // 512   attn out
  float* sH  = F + 3136;      // 2048  ffn hidden (ends 5184)
  float* sL  = F;             // 4096  logits-phase x rows (alias)
  float* sRed = F + 5200;     // 8
  float* sMu  = F + 5208;     // 8
  float* sSd  = F + 5216;     // 8
  unsigned short* key16 = (unsigned short*)smem;         // 32000 (64000B, sample phase)
  unsigned* histA = (unsigned*)(smem + 64000);           // 256
  unsigned* sKeys = (unsigned*)(smem + 64000);           // alias after hist passes (256 u32)
  unsigned* sMeta = (unsigned*)(smem + 65024);           // 8 words
  float*    sWin  = (float*)(smem + 65056);              // 4
  int*      sWix  = (int*)(smem + 65072);                // 4

  const float SQD = (float)22.627416997969522;
  const float PEC = (float)(9.210340371976184 / 512.0);
  const float SQRT2 = (float)1.4142135623730951;

  auto gbarg = [&]() {   // group barrier: 32 blocks, 4 sub-counters
    asm volatile("s_waitcnt vmcnt(0)" ::: "memory");
    __syncthreads();
    ++gp;
    if (tid == 0) {
      unsigned* c = bars + g * 128;
      __hip_atomic_fetch_add(&c[(gid & 3) * 32], 1u, __ATOMIC_RELAXED, SCOPE);
      unsigned tgt = gp * 8u;
      for (;;) {
        unsigned s0 = ldu(&c[0]), s1 = ldu(&c[32]), s2 = ldu(&c[64]), s3 = ldu(&c[96]);
        unsigned mn = s0 < s1 ? s0 : s1;
        unsigned mn2 = s2 < s3 ? s2 : s3;
        if ((mn < mn2 ? mn : mn2) >= tgt) break;
        __builtin_amdgcn_s_sleep(1);
      }
    }
    asm volatile("" ::: "memory");
    __syncthreads();
  };
  auto gbarall = [&]() { // global barrier: 256 blocks, 16 sub-counters
    asm volatile("s_waitcnt vmcnt(0)" ::: "memory");
    __syncthreads();
    ++glp;
    if (tid == 0) {
      unsigned* c = bars + 1024;
      __hip_atomic_fetch_add(&c[(bid & 15) * 32], 1u, __ATOMIC_RELAXED, SCOPE);
      unsigned tgt = glp * 16u;
      for (;;) {
        unsigned mn = 0xFFFFFFFFu;
#pragma unroll
        for (int i = 0; i < 16; i++) { unsigned x = ldu(&c[i * 32]); mn = x < mn ? x : mn; }
        if (mn >= tgt) break;
        __builtin_amdgcn_s_sleep(1);
      }
    }
    asm volatile("" ::: "memory");
    __syncthreads();
  };

  auto ln_local = [&](const float* src, const float* gamma, const float* beta, float* dst) {
    float2 v = ld2(src + 2 * tid);
    float s = wredf(v.x + v.y);
    if (lane == 0) sRed[w] = s;
    __syncthreads();
    float mu = (sRed[0] + sRed[1] + sRed[2] + sRed[3]) * (1.0f / 512.0f);
    __syncthreads();
    float d0 = v.x - mu, d1 = v.y - mu;
    float q = wredf(d0 * d0 + d1 * d1);
    if (lane == 0) sRed[w] = q;
    __syncthreads();
    float sd = sqrtf((sRed[0] + sRed[1] + sRed[2] + sRed[3]) * (1.0f / 512.0f) + 1e-5f);
    dst[2 * tid]     = d0 / sd * gamma[2 * tid]     + beta[2 * tid];
    dst[2 * tid + 1] = d1 / sd * gamma[2 * tid + 1] + beta[2 * tid + 1];
    __syncthreads();
  };

  auto wdot512 = [&](const float* wrow, const float* xs) -> float {
    const float4* wr4 = (const float4*)wrow;
    const float4* x4 = (const float4*)xs;
    float4 a0 = wr4[lane], a1 = wr4[lane + 64];
    float4 x0 = x4[lane], x1 = x4[lane + 64];
    return wredf(DOT8(a0, a1, x0, x1));
  };

  // ---- initial: embed BOS at position 0 (gid==0 block of each group) ----
  if (gid == 0) {
    const float* er = emb + (size_t)BOS_ID * D;
    int j0 = 2 * tid;
    st2(&xcur[g * D + j0], er[j0] * SQD + 0.0f, er[j0 + 1] * SQD + 1.0f);
  }
  gbarg();

  for (int t = 0; t < STEPS; ++t) {
    const int T = t + 1;
    for (int l = 0; l < NL; ++l) {
      const float* wqkv0 = qkv_w + ((size_t)l * 2 + 0) * (3 * D) * D;
      const float* bqkv0 = qkv_b + ((size_t)l * 2 + 0) * (3 * D);
      const float* wqkv1 = qkv_w + ((size_t)l * 2 + 1) * (3 * D) * D;
      const float* bqkv1 = qkv_b + ((size_t)l * 2 + 1) * (3 * D);
      const float* wo0 = out_w + ((size_t)l * 2 + 0) * D * D;
      const float* bo0 = out_b + ((size_t)l * 2 + 0) * D;
      const float* wo1 = out_w + ((size_t)l * 2 + 1) * D * D;
      const float* bo1 = out_b + ((size_t)l * 2 + 1) * D;

      // ---- P1: x1 = (l==0 ? xcur : LN(xt4)); QKV rows 48/block ----
      if (l == 0) {
        float2 v = ld2(&xcur[g * D + 2 * tid]);
        sX1[2 * tid] = v.x; sX1[2 * tid + 1] = v.y;
        __syncthreads();
      } else {
        ln_local(&xt4[g * D], lng + ((size_t)(l - 1) * 3 + 2) * D,
                 lnb + ((size_t)(l - 1) * 3 + 2) * D, sX1);
      }
      for (int r = 0; r < 12; ++r) {
        int j = gid * 48 + w * 12 + r;                    // 0..1535
        float acc = wdot512(wqkv0 + (size_t)j * D, sX1);
        if (lane == 0) {
          float v = acc + bqkv0[j];
          if (j < D)          st1(&qS[g * D + j], v);
          else if (j < 2 * D) st1(&Kc[(((size_t)l * BB + g) * TMAX + t) * D + (j - D)], v);
          else                st1(&Vc[(((size_t)l * BB + g) * TMAX + t) * D + (j - 2 * D)], v);
        }
      }
      gbarg();

      // ---- P2: self-attn (redundant per block) + Wo rows 16/block + residual ----
      {
        float2 v = ld2(&qS[g * D + 2 * tid]);
        sQ[2 * tid] = v.x; sQ[2 * tid + 1] = v.y;
      }
      __syncthreads();
      if (tid < NH * T) {
        int h = tid / T, k = tid - h * T;
        const float* Kr = Kc + (((size_t)l * BB + g) * TMAX + k) * D + h * HD;
        float sc = 0.f;
        for (int e = 0; e < 32; e++) {
          float2 kk = ld2(Kr + 2 * e);
          sc += kk.x * sQ[h * HD + 2 * e] + kk.y * sQ[h * HD + 2 * e + 1];
        }
        sS[h * TMAX + k] = sc * 0.125f;
      }
      __syncthreads();
      {
        int h = w * 2 + (lane >> 5), l5 = lane & 31;
        float v = (l5 < T) ? sS[h * TMAX + l5] : -INFINITY;
        float m = v;
        for (int o = 16; o; o >>= 1) m = fmaxf(m, __shfl_xor(m, o, 64));
        float p = (l5 < T) ? expf(v - m) : 0.f;
        float den = p;
        for (int o = 16; o; o >>= 1) den += __shfl_xor(den, o, 64);
        if (l5 < T) sSP[h * TMAX + l5] = p / den;
      }
      __syncthreads();
#pragma unroll
      for (int half = 0; half < 2; ++half) {
        int o = tid + half * 256;
        int h = o >> 6, d = o & 63;
        const float* Vb = Vc + (((size_t)l * BB + g) * TMAX) * D + h * HD + d;
        float acc = 0.f;
        for (int k = 0; k < T; k++) acc += sSP[h * TMAX + k] * ld1(Vb + (size_t)k * D);
        sAO[o] = acc;
      }
      __syncthreads();
      for (int r = 0; r < 4; ++r) {
        int j = gid * 16 + w * 4 + r;
        float acc = wdot512(wo0 + (size_t)j * D, sAO);
        if (lane == 0) st1(&xt2[g * D + j], acc + bo0[j] + sX1[j]);
      }
      gbarg();

      // ---- P3: x2 = LN(xt2); cross-Q rows 16/block ----
      ln_local(&xt2[g * D], lng + ((size_t)l * 3 + 0) * D, lnb + ((size_t)l * 3 + 0) * D, sX2);
      for (int r = 0; r < 4; ++r) {
        int j = gid * 16 + w * 4 + r;
        float acc = wdot512(wqkv1 + (size_t)j * D, sX2);
        if (lane == 0) st1(&q2S[g * D + j], acc + bqkv1[j]);
      }
      gbarg();

      // ---- P4: cross-attn (redundant, cached cK/cV) + Wo2 + residual(x2) ----
      {
        float2 v = ld2(&q2S[g * D + 2 * tid]);
        sQ[2 * tid] = v.x; sQ[2 * tid + 1] = v.y;
      }
      __syncthreads();
#pragma unroll
      for (int half = 0; half < 2; ++half) {
        int pr = tid + half * 256;
        int h = pr >> 6, k = pr & 63;
        const float4* Kr = (const float4*)(cK + (((size_t)l * BB + g) * KC + k) * D + h * HD);
        const float4* q4 = (const float4*)(sQ + h * HD);
        float sc = 0.f;
#pragma unroll
        for (int e = 0; e < 16; e++) {
          float4 a = Kr[e], b = q4[e];
          sc += a.x * b.x + a.y * b.y + a.z * b.z + a.w * b.w;
        }
        sS[h * KC + k] = sc * 0.125f;
      }
      __syncthreads();
#pragma unroll
      for (int hh = 0; hh < 2; ++hh) {
        int h = w * 2 + hh;
        float v = sS[h * KC + lane];
        float m = wredmaxf(v);
        float p = expf(v - m);
        float den = wredf(p);
        sSP[h * KC + lane] = p / den;
      }
      __syncthreads();
#pragma unroll
      for (int half = 0; half < 2; ++half) {
        int o = tid + half * 256;
        int h = o >> 6, d = o & 63;
        const float* Vb = cV + (((size_t)l * BB + g) * KC) * D + h * HD + d;
        float acc = 0.f;
        for (int k = 0; k < KC; k++) acc += sSP[h * KC + k] * Vb[(size_t)k * D];
        sAO[o] = acc;
      }
      __syncthreads();
      for (int r = 0; r < 4; ++r) {
        int j = gid * 16 + w * 4 + r;
        float acc = wdot512(wo1 + (size_t)j * D, sAO);
        if (lane == 0) st1(&xt3[g * D + j], acc + bo1[j] + sX2[j]);
      }
      gbarg();

      // ---- P5: x3 = LN(xt3) -> sX1; FFN1 rows 64/block + GELU ----
      ln_local(&xt3[g * D], lng + ((size_t)l * 3 + 1) * D, lnb + ((size_t)l * 3 + 1) * D, sX1);
      for (int r = 0; r < 16; ++r) {
        int j = gid * 64 + w * 16 + r;                    // 0..2047
        float acc = wdot512(f_w1 + (size_t)l * DFF * D + (size_t)j * D, sX1);
        if (lane == 0) {
          float v = acc + f_b1[(size_t)l * DFF + j];
          v = v * (erff(v / SQRT2) + 1.0f) / 2.0f;
          st1(&hB[g * DFF + j], v);
        }
      }
      gbarg();

      // ---- P6: FFN2 rows 16/block (full 2048-dot: 8 x float4 per lane) + residual(x3) ----
      for (int ii = tid; ii < 1024; ii += 256) {
        float2 v = ld2(&hB[g * DFF + 2 * ii]);
        sH[2 * ii] = v.x; sH[2 * ii + 1] = v.y;
      }
      __syncthreads();
      for (int r = 0; r < 4; ++r) {
        int j = gid * 16 + w * 4 + r;
        const float4* wr4 = (const float4*)(f_w2 + (size_t)l * D * DFF + (size_t)j * DFF);
        const float4* h4 = (const float4*)sH;
        float acc = 0.f;
#pragma unroll
        for (int q4i = 0; q4i < 8; ++q4i) {
          float4 a = wr4[lane + q4i * 64];
          float4 xx = h4[lane + q4i * 64];
          acc += a.x * xx.x + a.y * xx.y + a.z * xx.z + a.w * xx.w;
        }
        acc = wredf(acc);
        if (lane == 0) st1(&xt4[g * D + j], acc + f_b2[(size_t)l * D + j] + sX1[j]);
      }
      if (l < NL - 1) gbarg(); else gbarall();
    } // l

    // ---- logits: all blocks; xf = LN(xt4, ln[3,2]); vocab cols 125/block ----
    for (int ii = tid; ii < 2048; ii += 256) {
      float2 v = ld2(&xt4[2 * ii]);
      sL[2 * ii] = v.x; sL[2 * ii + 1] = v.y;
    }
    __syncthreads();
    {
      int b = w * 2 + (lane >> 5), l5 = lane & 31;
      float s = 0.f;
      for (int e = l5; e < D; e += 32) s += sL[b * D + e];
      for (int o = 16; o; o >>= 1) s += __shfl_xor(s, o, 64);
      if (l5 == 0) sMu[b] = s * (1.0f / 512.0f);
      __syncthreads();
      float mu = sMu[b], q = 0.f;
      for (int e = l5; e < D; e += 32) { float d0 = sL[b * D + e] - mu; q += d0 * d0; }
      for (int o = 16; o; o >>= 1) q += __shfl_xor(q, o, 64);
      if (l5 == 0) sSd[b] = sqrtf(q * (1.0f / 512.0f) + 1e-5f);
      __syncthreads();
      const float* ga = lng + 11 * D;
      const float* be = lnb + 11 * D;
      for (int ii = tid; ii < 4096; ii += 256) {
        int b2 = ii >> 9, e = ii & 511;
        sL[ii] = (sL[ii] - sMu[b2]) / sSd[b2] * ga[e] + be[e];
      }
      __syncthreads();
    }
    for (int i = w; i < 125; i += 4) {
      int v = i * 256 + bid;
      const float4* er = (const float4*)(emb + (size_t)v * D);
      float4 e0 = er[lane], e1 = er[lane + 64];
      float acc[8];
#pragma unroll
      for (int b = 0; b < 8; b++) {
        const float4* x4 = (const float4*)(sL + b * D);
        float4 x0 = x4[lane], x1 = x4[lane + 64];
        acc[b] = DOT8(e0, e1, x0, x1);
      }
#pragma unroll
      for (int o = 32; o; o >>= 1) {
#pragma unroll
        for (int b = 0; b < 8; b++) acc[b] += __shfl_xor(acc[b], o, 64);
      }
      if (lane == 0) {
#pragma unroll
        for (int b = 0; b < 8; b++) st1(&lg[(size_t)b * NV + v], acc[b]);
      }
    }
    gbarall();

    // ---- sample (gid==0 block per group): exact top-k via LDS key16 radix ----
    if (gid == 0) {
      int b = g;
      histA[tid] = 0u;
      __syncthreads();
      for (int v2 = tid; v2 < NV / 2; v2 += 256) {
        float2 f = ld2(&lg[(size_t)b * NV + 2 * v2]);
        unsigned u0 = monok(f.x), u1 = monok(f.y);
        key16[2 * v2] = (unsigned short)(u0 >> 16);
        key16[2 * v2 + 1] = (unsigned short)(u1 >> 16);
        atomicAdd(&histA[u0 >> 24], 1u);
        atomicAdd(&histA[u1 >> 24], 1u);
      }
      __syncthreads();
      if (tid == 0) {
        unsigned k = KTOP, cum = 0;
        for (int bin = 255; bin >= 0; bin--) {
          cum += histA[bin];
          if (cum >= k) { sMeta[0] = (unsigned)bin; sMeta[1] = k - (cum - histA[bin]); break; }
        }
      }
      __syncthreads();
      unsigned selHi = sMeta[0], rem1 = sMeta[1];
      histA[tid] = 0u;
      __syncthreads();
      for (int v = tid; v < NV; v += 256) {
        unsigned k16 = key16[v];
        if ((k16 >> 8) == selHi) atomicAdd(&histA[k16 & 255u], 1u);
      }
      __syncthreads();
      if (tid == 0) {
        unsigned k = rem1, cum = 0;
        for (int bin = 255; bin >= 0; bin--) {
          cum += histA[bin];
          if (cum >= k) { sMeta[2] = (selHi << 8) | (unsigned)bin; sMeta[1] = k - (cum - histA[bin]); break; }
        }
        sMeta[3] = 0u;
      }
      __syncthreads();
      unsigned P16 = sMeta[2], rem2 = sMeta[1];
      for (int v = tid; v < NV; v += 256) {
        if (key16[v] == (unsigned short)P16) {
          unsigned i = atomicAdd(&sMeta[3], 1u);
          if (i < 256) sKeys[i] = monok(ld1(&lg[(size_t)b * NV + v]));
        }
      }
      __syncthreads();
      if (tid == 0) {
        unsigned n = sMeta[3]; if (n > 256) n = 256;
        unsigned thr = 0;
        for (unsigned it = 0; it < rem2; ++it) {
          unsigned bestk = 0; int bj = 0;
          for (unsigned jx = 0; jx < n; jx++)
            if (sKeys[jx] > bestk) { bestk = sKeys[jx]; bj = (int)jx; }
          thr = bestk;
          sKeys[bj] = 0u;
        }
        sMeta[5] = (thr & 0x80000000u) ? (thr ^ 0x80000000u) : ~thr;  // inverse monotone
      }
      __syncthreads();
      float th = __uint_as_float(sMeta[5]);
      unsigned k0, k1;
      tf2x32(0u, 1u, 0u, (unsigned)t, k0, k1);
      float best = -INFINITY; int bi = NV;
      for (int v = tid; v < NV; v += 256) {
        if (key16[v] >= (unsigned short)P16) {
          float lo = ld1(&lg[(size_t)b * NV + v]);
          if (lo >= th) {
            unsigned o0, o1;
            tf2x32(k0, k1, 0u, (unsigned)(b * NV + v), o0, o1);
            unsigned bits = o0 ^ o1;
            unsigned ub = (bits >> 9) | 0x3f800000u;
            float fu = __uint_as_float(ub) - 1.0f;
            const float TINY = 1.17549435e-38f;
            float u = fu * (1.0f - TINY) + TINY;
            u = fmaxf(TINY, u);
            float gmb = -logf(-logf(u));
            float s = lo + gmb;
            if (s > best || (s == best && v < bi)) { best = s; bi = v; }
          }
        }
      }
      for (int o = 32; o; o >>= 1) {
        float ob = __shfl_xor(best, o, 64); int ox = __shfl_xor(bi, o, 64);
        if (ob > best || (ob == best && ox < bi)) { best = ob; bi = ox; }
      }
      if (lane == 0) { sWin[w] = best; sWix[w] = bi; }
      __syncthreads();
      if (tid == 0) {
        float bb = sWin[0]; int bx = sWix[0];
        for (int i2 = 1; i2 < 4; i2++) {
          if (sWin[i2] > bb || (sWin[i2] == bb && sWix[i2] < bx)) { bb = sWin[i2]; bx = sWix[i2]; }
        }
        int tok = bx;
        if (finished) tok = PAD_ID;
        toks[b * TMAX + t + 1] = tok;
        if (tok == EOS_ID) finished = 1;
        sMeta[4] = (unsigned)tok;
      }
      __syncthreads();
      {
        int tok = (int)sMeta[4];
        const float* er = emb + (size_t)tok * D;
        int j0 = 2 * tid;
        float omega = expf(-(float)j0 * PEC);
        float val = (float)(t + 1) * omega;
        st2(&xcur[g * D + j0], er[j0] * SQD + sinf(val), er[j0 + 1] * SQD + cosf(val));
      }
    }
    gbarg();
  } // t
}

// ---------------- host orchestration ----------------
extern "C" void kernel_launch(void* const* d_in, const int* in_sizes, int n_in,
                              void* d_out, int out_size, void* d_ws, size_t ws_size,
                              hipStream_t stream)
{
  const float* state = (const float*)d_in[0];
  const float* emb   = (const float*)d_in[1];
  const float* qkv_w = (const float*)d_in[2];
  const float* qkv_b = (const float*)d_in[3];
  const float* out_w = (const float*)d_in[4];
  const float* out_b = (const float*)d_in[5];
  const float* f_w1  = (const float*)d_in[6];
  const float* f_b1  = (const float*)d_in[7];
  const float* f_w2  = (const float*)d_in[8];
  const float* f_b2  = (const float*)d_in[9];
  const float* lng   = (const float*)d_in[10];
  const float* lnb   = (const float*)d_in[11];

  float* ws = (float*)d_ws;
  float* cK   = ws;                                   // 4*8*64*512
  float* cV   = cK + (size_t)NL * BB * KC * D;
  float* Kc   = cV + (size_t)NL * BB * KC * D;        // 4*8*17*512
  float* Vc   = Kc + (size_t)NL * BB * TMAX * D;
  float* qS   = Vc + (size_t)NL * BB * TMAX * D;      // 4096 each below
  float* q2S  = qS + BB * D;
  float* xt2  = q2S + BB * D;
  float* xt3  = xt2 + BB * D;
  float* xt4  = xt3 + BB * D;
  float* hB   = xt4 + BB * D;                         // 8*2048
  float* xcur = hB + BB * DFF;
  float* lg   = xcur + BB * D;                        // 8*32000
  unsigned* bars = (unsigned*)(lg + (size_t)BB * NV); // 2048 u32

  int* toks = (int*)d_out;

  init_k<<<1, 256, 0, stream>>>(toks, bars);
  cross_kv_k<<<dim3(NL * KC * 32, BB), 256, 0, stream>>>(state, qkv_w, qkv_b, cK, cV);
  decode_k<<<256, 256, 0, stream>>>(emb, qkv_w, qkv_b, out_w, out_b,
                                    f_w1, f_b1, f_w2, f_b2, lng, lnb,
                                    cK, cV, Kc, Vc, qS, q2S,
                                    xt2, xt3, xt4, hB, xcur, lg, bars, toks);
}

// Round 6
// 6056.242 us; speedup vs baseline: 1.9780x; 1.2142x over previous
//
#include <hip/hip_runtime.h>
#include <math.h>
#include <stdint.h>

#define D     512
#define DFF   2048
#define BB    8
#define NH    8
#define HD    64
#define NV    32000
#define NL    4
#define TMAX  17
#define KC    64
#define STEPS 16
#define KTOP  50
#define PAD_ID 0
#define BOS_ID 2
#define EOS_ID 3
#define SCOPE __HIP_MEMORY_SCOPE_AGENT

// ---------------- coherent (cache-bypassing) access -------------------------
__device__ __forceinline__ float ld1(const float* p) {
  return __hip_atomic_load(p, __ATOMIC_RELAXED, SCOPE);
}
__device__ __forceinline__ void st1(float* p, float v) {
  __hip_atomic_store(p, v, __ATOMIC_RELAXED, SCOPE);
}
__device__ __forceinline__ float2 ld2(const float* p) {
  union { double d; float2 f; } u;
  u.d = __hip_atomic_load((const double*)p, __ATOMIC_RELAXED, SCOPE);
  return u.f;
}
__device__ __forceinline__ unsigned ldu(const unsigned* p) {
  return __hip_atomic_load(p, __ATOMIC_RELAXED, SCOPE);
}

// ---------------- threefry2x32 (matches jax lowering exactly) ----------------
__device__ __forceinline__ void tf2x32(unsigned k0, unsigned k1, unsigned x0, unsigned x1,
                                       unsigned& o0, unsigned& o1)
{
  unsigned ks2 = k0 ^ k1 ^ 0x1BD11BDAu;
#define TFR(r) { x0 += x1; x1 = (x1 << (r)) | (x1 >> (32 - (r))); x1 ^= x0; }
  x0 += k0; x1 += k1;
  TFR(13) TFR(15) TFR(26) TFR(6)
  x0 += k1;  x1 += ks2 + 1u;
  TFR(17) TFR(29) TFR(16) TFR(24)
  x0 += ks2; x1 += k0 + 2u;
  TFR(13) TFR(15) TFR(26) TFR(6)
  x0 += k0;  x1 += k1 + 3u;
  TFR(17) TFR(29) TFR(16) TFR(24)
  x0 += k1;  x1 += ks2 + 4u;
  TFR(13) TFR(15) TFR(26) TFR(6)
  o0 = x0 + ks2; o1 = x1 + k0 + 5u;
#undef TFR
}

__device__ __forceinline__ float wredf(float v) {
  for (int o = 32; o; o >>= 1) v += __shfl_xor(v, o, 64);
  return v;
}
__device__ __forceinline__ float wredmaxf(float v) {
  for (int o = 32; o; o >>= 1) v = fmaxf(v, __shfl_xor(v, o, 64));
  return v;
}
__device__ __forceinline__ unsigned monok(float f) {
  unsigned u = __float_as_uint(f);
  return (u & 0x80000000u) ? ~u : (u | 0x80000000u);
}

#define DOT8(a0,a1,x0,x1) (a0.x*x0.x + a0.y*x0.y + a0.z*x0.z + a0.w*x0.w + \
                           a1.x*x1.x + a1.y*x1.y + a1.z*x1.z + a1.w*x1.w)

// ---------------- init: BOS tokens + barrier state --------------------------
__global__ void init_k(int* toks, unsigned* bars)
{
  int i = threadIdx.x;
  if (i < BB) toks[i * TMAX] = BOS_ID;
  for (int k = i; k < 2048; k += 256) bars[k] = 0u;
}

// ---------------- cross-attention K/V precompute (one-time) -----------------
__global__ void cross_kv_k(const float* __restrict__ state, const float* __restrict__ qkvw,
                           const float* __restrict__ qkvb, float* __restrict__ cK,
                           float* __restrict__ cV)
{
  int gx = blockIdx.x, b = blockIdx.y, tid = threadIdx.x;
  int jblk = gx & 31, kpos = (gx >> 5) & 63, l = gx >> 11;
  int w = tid >> 6, lane = tid & 63;
  __shared__ __align__(16) float xsh[D];
  xsh[tid] = state[((size_t)b * KC + kpos) * D + tid];
  xsh[tid + 256] = state[((size_t)b * KC + kpos) * D + tid + 256];
  __syncthreads();
  for (int i = 0; i < 8; i++) {
    int j = jblk * 32 + w * 8 + i;          // 0..1023 (K rows then V rows)
    int row = D + j;
    const float4* wr = (const float4*)(qkvw + (((size_t)l * 2 + 1) * (3 * D) + row) * D);
    const float4* x4 = (const float4*)xsh;
    float acc = 0.f;
    for (int e = lane; e < 128; e += 64) {
      float4 a = wr[e], xx = x4[e];
      acc += a.x * xx.x + a.y * xx.y + a.z * xx.z + a.w * xx.w;
    }
    acc = wredf(acc);
    if (lane == 0) {
      float v = acc + qkvb[((size_t)l * 2 + 1) * (3 * D) + row];
      float* dst = (j < D) ? cK : cV;
      int jj = (j < D) ? j : j - D;
      dst[(((size_t)l * BB + b) * KC + kpos) * D + jj] = v;
    }
  }
}

// ---------------- persistent grouped decode kernel --------------------------
extern "C" __global__ void __launch_bounds__(512, 2)
decode_k(const float* __restrict__ emb, const float* __restrict__ qkv_w,
         const float* __restrict__ qkv_b, const float* __restrict__ out_w,
         const float* __restrict__ out_b, const float* __restrict__ f_w1,
         const float* __restrict__ f_b1, const float* __restrict__ f_w2,
         const float* __restrict__ f_b2, const float* __restrict__ lng,
         const float* __restrict__ lnb,
         const float* __restrict__ cK, const float* __restrict__ cV,
         float* Kc, float* Vc, float* qS, float* q2S,
         float* xt2, float* xt3, float* xt4, float* hB,
         float* xcur, float* lg, unsigned* bars, int* toks)
{
  const int tid = threadIdx.x, bid = blockIdx.x;
  const int g = bid & 7, gid = bid >> 3;     // group (=batch row, ~XCD) / in-group id
  const int w = tid >> 6, lane = tid & 63;
  unsigned gp = 0, glp = 0;
  int finished = 0;                          // used by gid==0 blocks only

  __shared__ __align__(16) unsigned char smem[65280];
  float* F = (float*)smem;
  float* sX1 = F;             // 512   (x1 / x3)
  float* sX2 = F + 512;       // 512   (x2)
  float* sQ  = F + 1024;      // 512
  float* sS  = F + 1536;      // 544   scores
  float* sSP = F + 2080;      // 544   softmax probs
  float* sAO = F + 2624;      // 512   attn out
  float* sH  = F + 3136;      // 2048  ffn hidden (ends 5184)
  float* sL  = F;             // 4096  logits-phase x rows (alias)
  float* sRed = F + 5184;     // 8
  unsigned short* key16 = (unsigned short*)smem;         // 32000 (64000B, sample phase)
  unsigned* histA = (unsigned*)(smem + 64000);           // 256 u32
  unsigned* sKeys = (unsigned*)(smem + 64000);           // alias after hist passes
  unsigned* sMeta = (unsigned*)(smem + 65024);           // 8 words
  float*    sWin  = (float*)(smem + 65056);              // 8
  int*      sWix  = (int*)(smem + 65088);                // 8

  const float SQD = (float)22.627416997969522;
  const float PEC = (float)(9.210340371976184 / 512.0);
  const float SQRT2 = (float)1.4142135623730951;

  auto gbarg = [&]() {   // group barrier: 32 blocks, 4 sub-counters
    asm volatile("s_waitcnt vmcnt(0)" ::: "memory");
    __syncthreads();
    ++gp;
    if (tid == 0) {
      unsigned* c = bars + g * 128;
      __hip_atomic_fetch_add(&c[(gid & 3) * 32], 1u, __ATOMIC_RELAXED, SCOPE);
      unsigned tgt = gp * 8u;
      for (;;) {
        unsigned s0 = ldu(&c[0]), s1 = ldu(&c[32]), s2 = ldu(&c[64]), s3 = ldu(&c[96]);
        unsigned mn = s0 < s1 ? s0 : s1;
        unsigned mn2 = s2 < s3 ? s2 : s3;
        if ((mn < mn2 ? mn : mn2) >= tgt) break;
        __builtin_amdgcn_s_sleep(1);
      }
    }
    asm volatile("" ::: "memory");
    __syncthreads();
  };
  auto gbarall = [&]() { // global barrier: 256 blocks, 16 sub-counters
    asm volatile("s_waitcnt vmcnt(0)" ::: "memory");
    __syncthreads();
    ++glp;
    if (tid == 0) {
      unsigned* c = bars + 1024;
      __hip_atomic_fetch_add(&c[(bid & 15) * 32], 1u, __ATOMIC_RELAXED, SCOPE);
      unsigned tgt = glp * 16u;
      for (;;) {
        unsigned mn = 0xFFFFFFFFu;
#pragma unroll
        for (int i = 0; i < 16; i++) { unsigned x = ldu(&c[i * 32]); mn = x < mn ? x : mn; }
        if (mn >= tgt) break;
        __builtin_amdgcn_s_sleep(1);
      }
    }
    asm volatile("" ::: "memory");
    __syncthreads();
  };

  // 512-thread LayerNorm: each thread owns one element
  auto ln_local = [&](const float* src, const float* gamma, const float* beta, float* dst) {
    float v = ld1(src + tid);
    float s = wredf(v);
    if (lane == 0) sRed[w] = s;
    __syncthreads();
    float mu = (sRed[0] + sRed[1] + sRed[2] + sRed[3] +
                sRed[4] + sRed[5] + sRed[6] + sRed[7]) * (1.0f / 512.0f);
    __syncthreads();
    float d0 = v - mu;
    float q = wredf(d0 * d0);
    if (lane == 0) sRed[w] = q;
    __syncthreads();
    float sd = sqrtf((sRed[0] + sRed[1] + sRed[2] + sRed[3] +
                      sRed[4] + sRed[5] + sRed[6] + sRed[7]) * (1.0f / 512.0f) + 1e-5f);
    dst[tid] = d0 / sd * gamma[tid] + beta[tid];
    __syncthreads();
  };

  // ---- initial: embed BOS at position 0 (gid==0 block of each group) ----
  if (gid == 0) {
    float pe = (tid & 1) ? 1.0f : 0.0f;     // cos(0), sin(0)
    st1(&xcur[g * D + tid], emb[(size_t)BOS_ID * D + tid] * SQD + pe);
  }
  gbarg();

  for (int t = 0; t < STEPS; ++t) {
    const int T = t + 1;
    for (int l = 0; l < NL; ++l) {
      const float* wqkv0 = qkv_w + ((size_t)l * 2 + 0) * (3 * D) * D;
      const float* bqkv0 = qkv_b + ((size_t)l * 2 + 0) * (3 * D);
      const float* wqkv1 = qkv_w + ((size_t)l * 2 + 1) * (3 * D) * D;
      const float* bqkv1 = qkv_b + ((size_t)l * 2 + 1) * (3 * D);
      const float* wo0 = out_w + ((size_t)l * 2 + 0) * D * D;
      const float* bo0 = out_b + ((size_t)l * 2 + 0) * D;
      const float* wo1 = out_w + ((size_t)l * 2 + 1) * D * D;
      const float* bo1 = out_b + ((size_t)l * 2 + 1) * D;

      // ---- P1: x1 = (l==0 ? xcur : LN(xt4)); QKV 6 rows/wave, batched ----
      if (l == 0) {
        sX1[tid] = ld1(&xcur[g * D + tid]);
        __syncthreads();
      } else {
        ln_local(&xt4[g * D], lng + ((size_t)(l - 1) * 3 + 2) * D,
                 lnb + ((size_t)(l - 1) * 3 + 2) * D, sX1);
      }
      {
        const float4 x0 = ((const float4*)sX1)[lane], x1v = ((const float4*)sX1)[lane + 64];
        const int jbase = gid * 48 + w * 6;
        float4 wa[6], wb[6];
#pragma unroll
        for (int r = 0; r < 6; ++r) {
          const float4* w4 = (const float4*)(wqkv0 + (size_t)(jbase + r) * D);
          wa[r] = w4[lane]; wb[r] = w4[lane + 64];
        }
        float acc[6];
#pragma unroll
        for (int r = 0; r < 6; ++r) acc[r] = DOT8(wa[r], wb[r], x0, x1v);
#pragma unroll
        for (int o = 32; o; o >>= 1) {
#pragma unroll
          for (int r = 0; r < 6; ++r) acc[r] += __shfl_xor(acc[r], o, 64);
        }
        if (lane == 0) {
#pragma unroll
          for (int r = 0; r < 6; ++r) {
            int j = jbase + r;
            float v = acc[r] + bqkv0[j];
            if (j < D)          st1(&qS[g * D + j], v);
            else if (j < 2 * D) st1(&Kc[(((size_t)l * BB + g) * TMAX + t) * D + (j - D)], v);
            else                st1(&Vc[(((size_t)l * BB + g) * TMAX + t) * D + (j - 2 * D)], v);
          }
        }
      }
      gbarg();

      // ---- P2: self-attn (redundant per block, cached K/V) + Wo + residual ----
      sQ[tid] = ld1(&qS[g * D + tid]);
      __syncthreads();
      if (tid < NH * T) {
        int h = tid / T, k = tid - h * T;
        const float4* Kr = (const float4*)(Kc + (((size_t)l * BB + g) * TMAX + k) * D + h * HD);
        const float4* q4 = (const float4*)(sQ + h * HD);
        float sc = 0.f;
#pragma unroll
        for (int e = 0; e < 16; ++e) {
          float4 a = Kr[e], b2 = q4[e];
          sc += a.x * b2.x + a.y * b2.y + a.z * b2.z + a.w * b2.w;
        }
        sS[h * TMAX + k] = sc * 0.125f;
      }
      __syncthreads();
      {
        int h = w;
        float v = (lane < T) ? sS[h * TMAX + lane] : -INFINITY;
        float m = wredmaxf(v);
        float p = (lane < T) ? expf(v - m) : 0.f;
        float den = wredf(p);
        if (lane < T) sSP[h * TMAX + lane] = p / den;
      }
      __syncthreads();
      {
        int h = w;
        const float* Vb = Vc + (((size_t)l * BB + g) * TMAX) * D + h * HD + lane;
        float acc = 0.f;
        for (int k = 0; k < T; ++k) acc += sSP[h * TMAX + k] * Vb[(size_t)k * D];
        sAO[tid] = acc;
      }
      __syncthreads();
      {
        const float4 x0 = ((const float4*)sAO)[lane], x1v = ((const float4*)sAO)[lane + 64];
        const int jbase = gid * 16 + w * 2;
        float4 wa[2], wb[2];
#pragma unroll
        for (int r = 0; r < 2; ++r) {
          const float4* w4 = (const float4*)(wo0 + (size_t)(jbase + r) * D);
          wa[r] = w4[lane]; wb[r] = w4[lane + 64];
        }
        float acc[2];
#pragma unroll
        for (int r = 0; r < 2; ++r) acc[r] = DOT8(wa[r], wb[r], x0, x1v);
#pragma unroll
        for (int o = 32; o; o >>= 1) {
#pragma unroll
          for (int r = 0; r < 2; ++r) acc[r] += __shfl_xor(acc[r], o, 64);
        }
        if (lane == 0) {
#pragma unroll
          for (int r = 0; r < 2; ++r) {
            int j = jbase + r;
            st1(&xt2[g * D + j], acc[r] + bo0[j] + sX1[j]);
          }
        }
      }
      gbarg();

      // ---- P3: x2 = LN(xt2); cross-Q 2 rows/wave ----
      ln_local(&xt2[g * D], lng + ((size_t)l * 3 + 0) * D, lnb + ((size_t)l * 3 + 0) * D, sX2);
      {
        const float4 x0 = ((const float4*)sX2)[lane], x1v = ((const float4*)sX2)[lane + 64];
        const int jbase = gid * 16 + w * 2;
        float4 wa[2], wb[2];
#pragma unroll
        for (int r = 0; r < 2; ++r) {
          const float4* w4 = (const float4*)(wqkv1 + (size_t)(jbase + r) * D);
          wa[r] = w4[lane]; wb[r] = w4[lane + 64];
        }
        float acc[2];
#pragma unroll
        for (int r = 0; r < 2; ++r) acc[r] = DOT8(wa[r], wb[r], x0, x1v);
#pragma unroll
        for (int o = 32; o; o >>= 1) {
#pragma unroll
          for (int r = 0; r < 2; ++r) acc[r] += __shfl_xor(acc[r], o, 64);
        }
        if (lane == 0) {
#pragma unroll
          for (int r = 0; r < 2; ++r) {
            int j = jbase + r;
            st1(&q2S[g * D + j], acc[r] + bqkv1[j]);
          }
        }
      }
      gbarg();

      // ---- P4: cross-attn (redundant, cached cK/cV) + Wo2 + residual(x2) ----
      sQ[tid] = ld1(&q2S[g * D + tid]);
      __syncthreads();
      {
        int h = w, k = lane;
        const float4* Kr = (const float4*)(cK + (((size_t)l * BB + g) * KC + k) * D + h * HD);
        const float4* q4 = (const float4*)(sQ + h * HD);
        float sc = 0.f;
#pragma unroll
        for (int e = 0; e < 16; ++e) {
          float4 a = Kr[e], b2 = q4[e];
          sc += a.x * b2.x + a.y * b2.y + a.z * b2.z + a.w * b2.w;
        }
        sS[h * 64 + k] = sc * 0.125f;
      }
      __syncthreads();
      {
        int h = w;
        float v = sS[h * 64 + lane];
        float m = wredmaxf(v);
        float p = expf(v - m);
        float den = wredf(p);
        sSP[h * 64 + lane] = p / den;
      }
      __syncthreads();
      {
        int h = w;
        const float* Vb = cV + (((size_t)l * BB + g) * KC) * D + h * HD + lane;
        float acc = 0.f;
        for (int k = 0; k < KC; ++k) acc += sSP[h * 64 + k] * Vb[(size_t)k * D];
        sAO[tid] = acc;
      }
      __syncthreads();
      {
        const float4 x0 = ((const float4*)sAO)[lane], x1v = ((const float4*)sAO)[lane + 64];
        const int jbase = gid * 16 + w * 2;
        float4 wa[2], wb[2];
#pragma unroll
        for (int r = 0; r < 2; ++r) {
          const float4* w4 = (const float4*)(wo1 + (size_t)(jbase + r) * D);
          wa[r] = w4[lane]; wb[r] = w4[lane + 64];
        }
        float acc[2];
#pragma unroll
        for (int r = 0; r < 2; ++r) acc[r] = DOT8(wa[r], wb[r], x0, x1v);
#pragma unroll
        for (int o = 32; o; o >>= 1) {
#pragma unroll
          for (int r = 0; r < 2; ++r) acc[r] += __shfl_xor(acc[r], o, 64);
        }
        if (lane == 0) {
#pragma unroll
          for (int r = 0; r < 2; ++r) {
            int j = jbase + r;
            st1(&xt3[g * D + j], acc[r] + bo1[j] + sX2[j]);
          }
        }
      }
      gbarg();

      // ---- P5: x3 = LN(xt3) -> sX1; FFN1 8 rows/wave + GELU ----
      ln_local(&xt3[g * D], lng + ((size_t)l * 3 + 1) * D, lnb + ((size_t)l * 3 + 1) * D, sX1);
      {
        const float4 x0 = ((const float4*)sX1)[lane], x1v = ((const float4*)sX1)[lane + 64];
        const int jbase = gid * 64 + w * 8;
        float4 wa[8], wb[8];
#pragma unroll
        for (int r = 0; r < 8; ++r) {
          const float4* w4 = (const float4*)(f_w1 + (size_t)l * DFF * D + (size_t)(jbase + r) * D);
          wa[r] = w4[lane]; wb[r] = w4[lane + 64];
        }
        float acc[8];
#pragma unroll
        for (int r = 0; r < 8; ++r) acc[r] = DOT8(wa[r], wb[r], x0, x1v);
#pragma unroll
        for (int o = 32; o; o >>= 1) {
#pragma unroll
          for (int r = 0; r < 8; ++r) acc[r] += __shfl_xor(acc[r], o, 64);
        }
        if (lane == 0) {
#pragma unroll
          for (int r = 0; r < 8; ++r) {
            int j = jbase + r;
            float v = acc[r] + f_b1[(size_t)l * DFF + j];
            v = v * (erff(v / SQRT2) + 1.0f) / 2.0f;
            st1(&hB[g * DFF + j], v);
          }
        }
      }
      gbarg();

      // ---- P6: FFN2 2 rows/wave (2048-dot) + residual(x3) ----
      for (int ii = tid; ii < 1024; ii += 512) {
        float2 v = ld2(&hB[g * DFF + 2 * ii]);
        sH[2 * ii] = v.x; sH[2 * ii + 1] = v.y;
      }
      __syncthreads();
      {
        float4 hx[8];
#pragma unroll
        for (int e = 0; e < 8; ++e) hx[e] = ((const float4*)sH)[lane + e * 64];
        const int jbase = gid * 16 + w * 2;
        float acc[2];
#pragma unroll
        for (int r = 0; r < 2; ++r) {
          const float4* w4 = (const float4*)(f_w2 + (size_t)l * D * DFF + (size_t)(jbase + r) * DFF);
          float a = 0.f;
#pragma unroll
          for (int e = 0; e < 8; ++e) {
            float4 aw = w4[lane + e * 64];
            a += aw.x * hx[e].x + aw.y * hx[e].y + aw.z * hx[e].z + aw.w * hx[e].w;
          }
          acc[r] = a;
        }
#pragma unroll
        for (int o = 32; o; o >>= 1) {
#pragma unroll
          for (int r = 0; r < 2; ++r) acc[r] += __shfl_xor(acc[r], o, 64);
        }
        if (lane == 0) {
#pragma unroll
          for (int r = 0; r < 2; ++r) {
            int j = jbase + r;
            st1(&xt4[g * D + j], acc[r] + f_b2[(size_t)l * D + j] + sX1[j]);
          }
        }
      }
      if (l < NL - 1) gbarg(); else gbarall();
    } // l

    // ---- logits: all blocks; xf = LN(xt4, ln[3,2]); vocab cols 125/block ----
    for (int ii = tid; ii < 2048; ii += 512) {
      float2 v = ld2(&xt4[2 * ii]);
      sL[2 * ii] = v.x; sL[2 * ii + 1] = v.y;
    }
    __syncthreads();
    {
      int b = w;   // wave per batch row
      float vals[8]; float s = 0.f;
#pragma unroll
      for (int e = 0; e < 8; ++e) { vals[e] = sL[b * D + lane + e * 64]; s += vals[e]; }
      s = wredf(s);
      float mu = s * (1.0f / 512.0f);
      float q = 0.f;
#pragma unroll
      for (int e = 0; e < 8; ++e) { float d0 = vals[e] - mu; q += d0 * d0; }
      q = wredf(q);
      float sd = sqrtf(q * (1.0f / 512.0f) + 1e-5f);
      const float* ga = lng + 11 * D;
      const float* be = lnb + 11 * D;
#pragma unroll
      for (int e = 0; e < 8; ++e)
        sL[b * D + lane + e * 64] = (vals[e] - mu) / sd * ga[lane + e * 64] + be[lane + e * 64];
    }
    __syncthreads();
    for (int i = w; i < 125; i += 8) {
      int v = i * 256 + bid;
      const float4* er = (const float4*)(emb + (size_t)v * D);
      float4 e0 = er[lane], e1 = er[lane + 64];
      float acc[8];
#pragma unroll
      for (int b = 0; b < 8; b++) {
        const float4* x4 = (const float4*)(sL + b * D);
        float4 x0 = x4[lane], x1v = x4[lane + 64];
        acc[b] = DOT8(e0, e1, x0, x1v);
      }
#pragma unroll
      for (int o = 32; o; o >>= 1) {
#pragma unroll
        for (int b = 0; b < 8; b++) acc[b] += __shfl_xor(acc[b], o, 64);
      }
      if (lane == 0) {
#pragma unroll
        for (int b = 0; b < 8; b++) st1(&lg[(size_t)b * NV + v], acc[b]);
      }
    }
    gbarall();

    // ---- sample (gid==0 block per group): exact top-k via LDS key16 radix ----
    if (gid == 0) {
      int b = g;
      if (tid < 256) histA[tid] = 0u;
      __syncthreads();
      for (int v2 = tid; v2 < NV / 2; v2 += 512) {
        float2 f = ld2(&lg[(size_t)b * NV + 2 * v2]);
        unsigned u0 = monok(f.x), u1 = monok(f.y);
        key16[2 * v2] = (unsigned short)(u0 >> 16);
        key16[2 * v2 + 1] = (unsigned short)(u1 >> 16);
        atomicAdd(&histA[u0 >> 24], 1u);
        atomicAdd(&histA[u1 >> 24], 1u);
      }
      __syncthreads();
      if (tid == 0) {
        unsigned k = KTOP, cum = 0;
        for (int bin = 255; bin >= 0; bin--) {
          cum += histA[bin];
          if (cum >= k) { sMeta[0] = (unsigned)bin; sMeta[1] = k - (cum - histA[bin]); break; }
        }
      }
      __syncthreads();
      unsigned selHi = sMeta[0], rem1 = sMeta[1];
      if (tid < 256) histA[tid] = 0u;
      __syncthreads();
      for (int v = tid; v < NV; v += 512) {
        unsigned k16 = key16[v];
        if ((k16 >> 8) == selHi) atomicAdd(&histA[k16 & 255u], 1u);
      }
      __syncthreads();
      if (tid == 0) {
        unsigned k = rem1, cum = 0;
        for (int bin = 255; bin >= 0; bin--) {
          cum += histA[bin];
          if (cum >= k) { sMeta[2] = (selHi << 8) | (unsigned)bin; sMeta[1] = k - (cum - histA[bin]); break; }
        }
        sMeta[3] = 0u;
      }
      __syncthreads();
      unsigned P16 = sMeta[2], rem2 = sMeta[1];
      for (int v = tid; v < NV; v += 512) {
        if (key16[v] == (unsigned short)P16) {
          unsigned i = atomicAdd(&sMeta[3], 1u);
          if (i < 256) sKeys[i] = monok(ld1(&lg[(size_t)b * NV + v]));
        }
      }
      __syncthreads();
      if (tid == 0) {
        unsigned n = sMeta[3]; if (n > 256) n = 256;
        unsigned thr = 0;
        for (unsigned it = 0; it < rem2; ++it) {
          unsigned bestk = 0; int bj = 0;
          for (unsigned jx = 0; jx < n; jx++)
            if (sKeys[jx] > bestk) { bestk = sKeys[jx]; bj = (int)jx; }
          thr = bestk;
          sKeys[bj] = 0u;
        }
        sMeta[5] = (thr & 0x80000000u) ? (thr ^ 0x80000000u) : ~thr;  // inverse monotone
      }
      __syncthreads();
      float th = __uint_as_float(sMeta[5]);
      unsigned k0, k1;
      tf2x32(0u, 1u, 0u, (unsigned)t, k0, k1);
      float best = -INFINITY; int bi = NV;
      for (int v = tid; v < NV; v += 512) {
        if (key16[v] >= (unsigned short)P16) {
          float lo = ld1(&lg[(size_t)b * NV + v]);
          if (lo >= th) {
            unsigned o0, o1;
            tf2x32(k0, k1, 0u, (unsigned)(b * NV + v), o0, o1);
            unsigned bits = o0 ^ o1;
            unsigned ub = (bits >> 9) | 0x3f800000u;
            float fu = __uint_as_float(ub) - 1.0f;
            const float TINY = 1.17549435e-38f;
            float u = fu * (1.0f - TINY) + TINY;
            u = fmaxf(TINY, u);
            float gmb = -logf(-logf(u));
            float s = lo + gmb;
            if (s > best || (s == best && v < bi)) { best = s; bi = v; }
          }
        }
      }
      for (int o = 32; o; o >>= 1) {
        float ob = __shfl_xor(best, o, 64); int ox = __shfl_xor(bi, o, 64);
        if (ob > best || (ob == best && ox < bi)) { best = ob; bi = ox; }
      }
      if (lane == 0) { sWin[w] = best; sWix[w] = bi; }
      __syncthreads();
      if (tid == 0) {
        float bb = sWin[0]; int bx = sWix[0];
        for (int i2 = 1; i2 < 8; i2++) {
          if (sWin[i2] > bb || (sWin[i2] == bb && sWix[i2] < bx)) { bb = sWin[i2]; bx = sWix[i2]; }
        }
        int tok = bx;
        if (finished) tok = PAD_ID;
        toks[b * TMAX + t + 1] = tok;
        if (tok == EOS_ID) finished = 1;
        sMeta[4] = (unsigned)tok;
      }
      __syncthreads();
      {
        int tok = (int)sMeta[4];
        float omega = expf(-(float)(tid & ~1) * PEC);
        float val = (float)(t + 1) * omega;
        float pe = (tid & 1) ? cosf(val) : sinf(val);
        st1(&xcur[g * D + tid], emb[(size_t)tok * D + tid] * SQD + pe);
      }
    }
    gbarg();
  } // t
}

// ---------------- host orchestration ----------------
extern "C" void kernel_launch(void* const* d_in, const int* in_sizes, int n_in,
                              void* d_out, int out_size, void* d_ws, size_t ws_size,
                              hipStream_t stream)
{
  const float* state = (const float*)d_in[0];
  const float* emb   = (const float*)d_in[1];
  const float* qkv_w = (const float*)d_in[2];
  const float* qkv_b = (const float*)d_in[3];
  const float* out_w = (const float*)d_in[4];
  const float* out_b = (const float*)d_in[5];
  const float* f_w1  = (const float*)d_in[6];
  const float* f_b1  = (const float*)d_in[7];
  const float* f_w2  = (const float*)d_in[8];
  const float* f_b2  = (const float*)d_in[9];
  const float* lng   = (const float*)d_in[10];
  const float* lnb   = (const float*)d_in[11];

  float* ws = (float*)d_ws;
  float* cK   = ws;                                   // 4*8*64*512
  float* cV   = cK + (size_t)NL * BB * KC * D;
  float* Kc   = cV + (size_t)NL * BB * KC * D;        // 4*8*17*512
  float* Vc   = Kc + (size_t)NL * BB * TMAX * D;
  float* qS   = Vc + (size_t)NL * BB * TMAX * D;      // 4096 each below
  float* q2S  = qS + BB * D;
  float* xt2  = q2S + BB * D;
  float* xt3  = xt2 + BB * D;
  float* xt4  = xt3 + BB * D;
  float* hB   = xt4 + BB * D;                         // 8*2048
  float* xcur = hB + BB * DFF;
  float* lg   = xcur + BB * D;                        // 8*32000
  unsigned* bars = (unsigned*)(lg + (size_t)BB * NV); // 2048 u32

  int* toks = (int*)d_out;

  init_k<<<1, 256, 0, stream>>>(toks, bars);
  cross_kv_k<<<dim3(NL * KC * 32, BB), 256, 0, stream>>>(state, qkv_w, qkv_b, cK, cV);
  decode_k<<<256, 512, 0, stream>>>(emb, qkv_w, qkv_b, out_w, out_b,
                                    f_w1, f_b1, f_w2, f_b2, lng, lnb,
                                    cK, cV, Kc, Vc, qS, q2S,
                                    xt2, xt3, xt4, hB, xcur, lg, bars, toks);
}